// Round 4
// baseline (1643.432 us; speedup 1.0000x reference)
//
#include <hip/hip_runtime.h>
#include <hip/hip_bf16.h>

// Problem constants
#define BB 4
#define LL 900
#define DMODEL 256
#define DSTATE 16
#define DINNER 512
#define DTRANK 16
#define BL (BB*LL)          // 3600

__device__ __forceinline__ float silu_f(float v) { return v / (1.f + expf(-v)); }

// ---------------------------------------------------------------------------
// Transpose: out[c*R + r] = in[r*C + c]   (in: R x C, out: C x R)
// ---------------------------------------------------------------------------
__global__ void transpose_k(const float* __restrict__ in, float* __restrict__ out,
                            int R, int C)
{
    int idx = blockIdx.x * 256 + threadIdx.x;
    if (idx >= R * C) return;
    int c = idx / R, r = idx % R;
    out[idx] = in[(size_t)r * C + c];
}

// ---------------------------------------------------------------------------
// VALU GEMM: out[M,N] = A[M,K] @ W^T where WT[K,N] is the pre-transposed W.
// (exonerated in rounds 2/3: two independent impls agree)
// MODE 0: silu epilogue, split cols [0,512)->out0, [512,1024)->out1
// MODE 1: plain fp32 store, ld = N
// ---------------------------------------------------------------------------
template<int MODE>
__global__ void gemm_wt(const float* __restrict__ A,
                        const float* __restrict__ WT,
                        float* __restrict__ out0, float* __restrict__ out1,
                        int M, int N, int K)
{
    int col = blockIdx.x * blockDim.x + threadIdx.x;
    if (col >= N) return;
    int row0 = blockIdx.y * 8;
    float acc[8] = {0.f,0.f,0.f,0.f,0.f,0.f,0.f,0.f};
    const float* ap = A + (size_t)row0 * K;
    #pragma unroll 4
    for (int k = 0; k < K; ++k) {
        float wv = WT[(size_t)k * N + col];
        #pragma unroll
        for (int j = 0; j < 8; ++j)
            acc[j] = fmaf(ap[(size_t)j * K + k], wv, acc[j]);
    }
    #pragma unroll
    for (int j = 0; j < 8; ++j) {
        int row = row0 + j;
        float v = acc[j];
        if (MODE == 0) {
            float s = silu_f(v);
            if (col < DINNER) out0[(size_t)row * DINNER + col] = s;
            else              out1[(size_t)row * DINNER + (col - DINNER)] = s;
        } else {
            out0[(size_t)row * N + col] = v;
        }
    }
}

// ---------------------------------------------------------------------------
// Fully serial scan: one thread per (b, dir, d). All 16 states in registers.
// Computes dt inline from dtBC (cols 0..15) + W_dt + b_dt.
// zs is ALREADY silu'd (z_silu from stage 1).
// ycat[b,l, dir*512 + d] = (sum_n h*C + D*u) * zg
// ---------------------------------------------------------------------------
__global__ void scan_serial(const float* __restrict__ dtBC,   // [B,L,48]
                            const float* __restrict__ x,      // [B,L,512] silu'd
                            const float* __restrict__ zs,     // [B,L,512] silu'd
                            const float* __restrict__ Wdt,    // [512,16]
                            const float* __restrict__ bdt,    // [512]
                            const float* __restrict__ AlogF,  // [512,16]
                            const float* __restrict__ AlogB,
                            const float* __restrict__ Df,
                            const float* __restrict__ Db,
                            float* __restrict__ ycat)         // [B,L,1024]
{
    int b = blockIdx.z, dir = blockIdx.y;
    int d = blockIdx.x * 128 + threadIdx.x;
    const float* Alog = dir ? AlogB : AlogF;
    float a[DSTATE];
    #pragma unroll
    for (int n = 0; n < DSTATE; ++n) a[n] = -expf(Alog[d * DSTATE + n]);
    float Dd = dir ? Db[d] : Df[d];
    const float* wr = Wdt + (size_t)d * DTRANK;
    float wreg[DTRANK];
    #pragma unroll
    for (int k = 0; k < DTRANK; ++k) wreg[k] = wr[k];
    float bd = bdt[d];
    float h[DSTATE];
    #pragma unroll
    for (int n = 0; n < DSTATE; ++n) h[n] = 0.f;

    for (int i = 0; i < LL; ++i) {
        int l = dir ? (LL - 1 - i) : i;
        size_t base = (size_t)b * LL + l;
        const float* xr = dtBC + base * 48;
        // dt = softplus(dt_r . wdt + b_dt)
        float s = bd;
        #pragma unroll
        for (int k = 0; k < DTRANK; ++k) s = fmaf(xr[k], wreg[k], s);
        float dtv = (s > 20.f) ? s : log1pf(expf(s));
        float u = x[base * DINNER + d];
        float du = dtv * u;
        float p = 0.f;
        #pragma unroll
        for (int n = 0; n < DSTATE; ++n) {
            float dA = expf(dtv * a[n]);
            h[n] = fmaf(dA, h[n], du * xr[DTRANK + n]);
            p = fmaf(h[n], xr[DTRANK + DSTATE + n], p);
        }
        float zg = zs[base * DINNER + d];
        ycat[base * (2 * DINNER) + dir * DINNER + d] = (p + Dd * u) * zg;
    }
}

// ---------------------------------------------------------------------------
// Serial mean over L: one thread per (b, ch); 4096 threads.
// ---------------------------------------------------------------------------
__global__ void mean_serial(const float* __restrict__ ycat, float* __restrict__ ymean)
{
    int i = blockIdx.x * 256 + threadIdx.x;   // 4096
    int b = i >> 10, ch = i & 1023;
    float s = 0.f;
    for (int l = 0; l < LL; ++l)
        s += ycat[((size_t)b * LL + l) * (2 * DINNER) + ch];
    ymean[i] = s / (float)LL;
}

// ---------------------------------------------------------------------------
// Serial gemv: one thread per (b, j); vout[b,j] = vin[b,:] . W[j,:] + bias[j]
// ---------------------------------------------------------------------------
template<int SIG>
__global__ void gemv_serial(const float* __restrict__ vin,
                            const float* __restrict__ W,
                            const float* __restrict__ bias,
                            float* __restrict__ vout)
{
    int i = blockIdx.x * 256 + threadIdx.x;   // 4096
    int b = i >> 10, j = i & 1023;
    const float* wr = W + (size_t)j * 1024;
    const float* vr = vin + (size_t)b * 1024;
    float s = bias[j];
    for (int k = 0; k < 1024; ++k) s = fmaf(vr[k], wr[k], s);
    vout[i] = SIG ? (1.f / (1.f + expf(-s))) : s;
}

// ---------------------------------------------------------------------------
// y *= g[b,ch] (in place, fp32)
// ---------------------------------------------------------------------------
__global__ void scale_y(float* __restrict__ ycat, const float* __restrict__ g)
{
    size_t i = (size_t)blockIdx.x * 256 + threadIdx.x;
    if (i >= (size_t)BL * 1024) return;
    int ch = (int)(i & 1023);
    int b = (int)((i >> 10) / LL);
    ycat[i] = ycat[i] * g[b * 1024 + ch];
}

// ---------------------------------------------------------------------------
extern "C" void kernel_launch(void* const* d_in, const int* in_sizes, int n_in,
                              void* d_out, int out_size, void* d_ws, size_t ws_size,
                              hipStream_t stream)
{
    const float* hidden  = (const float*)d_in[0];
    const float* W_in    = (const float*)d_in[1];
    const float* W_xproj = (const float*)d_in[2];
    const float* W_dt    = (const float*)d_in[3];
    const float* b_dt    = (const float*)d_in[4];
    const float* A_log_f = (const float*)d_in[5];
    const float* A_log_b = (const float*)d_in[6];
    const float* D_f     = (const float*)d_in[7];
    const float* D_b     = (const float*)d_in[8];
    const float* W_glob  = (const float*)d_in[9];
    const float* b_glob  = (const float*)d_in[10];
    const float* W_gate  = (const float*)d_in[11];
    const float* b_gate  = (const float*)d_in[12];
    const float* W_out   = (const float*)d_in[13];
    float* out = (float*)d_out;

    // workspace layout (all fp32), ~33 MB total
    char* w = (char*)d_ws;
    float* x_silu = (float*)w; w += (size_t)BL * DINNER * 4;       // 7.37 MB
    float* z_silu = (float*)w; w += (size_t)BL * DINNER * 4;       // 7.37 MB
    float* dtBC   = (float*)w; w += (size_t)BL * 48 * 4;           // 0.69 MB
    float* ycat   = (float*)w; w += (size_t)BL * 2 * DINNER * 4;   // 14.7 MB
    float* ymean  = (float*)w; w += (size_t)BB * 1024 * 4;
    float* t1     = (float*)w; w += (size_t)BB * 1024 * 4;
    float* gbuf   = (float*)w; w += (size_t)BB * 1024 * 4;
    float* WT_in  = (float*)w; w += (size_t)DMODEL * 2 * DINNER * 4;     // 256x1024
    float* WT_xp  = (float*)w; w += (size_t)DINNER * 48 * 4;             // 512x48
    float* WT_out = (float*)w; w += (size_t)2 * DINNER * DMODEL * 4;     // 1024x256

    // 0) transpose weights for coalesced GEMM reads
    transpose_k<<<dim3((2*DINNER*DMODEL + 255)/256), dim3(256), 0, stream>>>(
        W_in, WT_in, 2*DINNER, DMODEL);
    transpose_k<<<dim3((48*DINNER + 255)/256), dim3(256), 0, stream>>>(
        W_xproj, WT_xp, 48, DINNER);
    transpose_k<<<dim3((DMODEL*2*DINNER + 255)/256), dim3(256), 0, stream>>>(
        W_out, WT_out, DMODEL, 2*DINNER);

    // 1) xz = hidden @ W_in^T, silu both halves -> x_silu, z_silu
    gemm_wt<0><<<dim3(4, BL/8), dim3(256), 0, stream>>>(
        hidden, WT_in, x_silu, z_silu, BL, 2*DINNER, DMODEL);
    // 2) x_dbl = x_silu @ W_xproj^T -> dtBC fp32 [BL,48]
    gemm_wt<1><<<dim3(1, BL/8), dim3(64), 0, stream>>>(
        x_silu, WT_xp, dtBC, nullptr, BL, 48, DINNER);
    // 3+4) dt inline + fully serial scan, fused *silu(z)
    scan_serial<<<dim3(DINNER/128, 2, BB), dim3(128), 0, stream>>>(
        dtBC, x_silu, z_silu, W_dt, b_dt, A_log_f, A_log_b, D_f, D_b, ycat);
    // 5) mean over L (serial)
    mean_serial<<<dim3(16), dim3(256), 0, stream>>>(ycat, ymean);
    // 6) gating (serial gemvs)
    gemv_serial<0><<<dim3(16), dim3(256), 0, stream>>>(ymean, W_glob, b_glob, t1);
    gemv_serial<1><<<dim3(16), dim3(256), 0, stream>>>(t1, W_gate, b_gate, gbuf);
    // 7) y *= g
    scale_y<<<dim3(BL * 1024 / 256), dim3(256), 0, stream>>>(ycat, gbuf);
    // 8) out = y @ W_out^T (fp32 out)
    gemm_wt<1><<<dim3(1, BL/8), dim3(256), 0, stream>>>(
        ycat, WT_out, out, nullptr, BL, DMODEL, 2*DINNER);
}

// Round 5
// 292.552 us; speedup vs baseline: 5.6176x; 5.6176x over previous
//
#include <hip/hip_runtime.h>
#include <hip/hip_bf16.h>

// Problem constants
#define BB 4
#define LL 900
#define DMODEL 256
#define DSTATE 16
#define DINNER 512
#define DTRANK 16
#define BL (BB*LL)          // 3600
#define NC 36               // scan chunks
#define LC 25               // steps per chunk; NC*LC == LL

typedef __bf16 bf16x8 __attribute__((ext_vector_type(8)));
typedef float f32x4 __attribute__((ext_vector_type(4)));

__device__ __forceinline__ float silu_f(float v) { return v / (1.f + expf(-v)); }

// Split 8 consecutive fp32 into bf16 hi + lo (v ~= hi+lo); exonerated round 2/3
__device__ __forceinline__ void split8(const float* __restrict__ p, bf16x8& hi, bf16x8& lo)
{
    const f32x4* q4 = reinterpret_cast<const f32x4*>(p);
    f32x4 v0 = q4[0], v1 = q4[1];
    #pragma unroll
    for (int j = 0; j < 4; ++j) {
        float v = v0[j];
        __bf16 h = (__bf16)v;
        hi[j] = h; lo[j] = (__bf16)(v - (float)h);
    }
    #pragma unroll
    for (int j = 0; j < 4; ++j) {
        float v = v1[j];
        __bf16 h = (__bf16)v;
        hi[4 + j] = h; lo[4 + j] = (__bf16)(v - (float)h);
    }
}

// ---------------------------------------------------------------------------
// MFMA GEMM (fp32 via bf16 hi/lo, 3 MFMA per 32-K chunk), C = A[M,K] @ B[N,K]^T
// One wave -> one 16x16 tile. MODE 0: silu + split to out0/out1. MODE 1: fp32.
// ---------------------------------------------------------------------------
template<int MODE>
__global__ void gemm_bt(const float* __restrict__ A,
                        const float* __restrict__ B,
                        float* __restrict__ out0, float* __restrict__ out1,
                        int M, int N, int K)
{
    int wave = (blockIdx.x * blockDim.x + threadIdx.x) >> 6;
    int ntN = N >> 4;
    int ntM = M >> 4;
    if (wave >= ntM * ntN) return;
    int tm = wave / ntN, tn = wave % ntN;
    int lane = threadIdx.x & 63;
    int q = lane >> 4;
    int r = lane & 15;
    const float* Arow = A + (size_t)(tm * 16 + r) * K + q * 8;
    const float* Brow = B + (size_t)(tn * 16 + r) * K + q * 8;
    f32x4 acc = {0.f, 0.f, 0.f, 0.f};
    for (int k0 = 0; k0 < K; k0 += 32) {
        bf16x8 ah, al, bh, bl;
        split8(Arow + k0, ah, al);
        split8(Brow + k0, bh, bl);
        acc = __builtin_amdgcn_mfma_f32_16x16x32_bf16(ah, bh, acc, 0, 0, 0);
        acc = __builtin_amdgcn_mfma_f32_16x16x32_bf16(ah, bl, acc, 0, 0, 0);
        acc = __builtin_amdgcn_mfma_f32_16x16x32_bf16(al, bh, acc, 0, 0, 0);
    }
    int col = tn * 16 + r;
    #pragma unroll
    for (int i = 0; i < 4; ++i) {
        int row = tm * 16 + q * 4 + i;
        float v = acc[i];
        if (MODE == 0) {
            float s = silu_f(v);
            if (col < DINNER) out0[(size_t)row * DINNER + col] = s;
            else              out1[(size_t)row * DINNER + (col - DINNER)] = s;
        } else {
            out0[(size_t)row * N + col] = v;
        }
    }
}

// ---------------------------------------------------------------------------
// dt = softplus(dtBC[:, :16] @ W_dt^T + b_dt) -> dtb[B,L,512]
// ---------------------------------------------------------------------------
__global__ void dt_kernel(const float* __restrict__ dtBC,
                          const float* __restrict__ Wdt,
                          const float* __restrict__ bdt,
                          float* __restrict__ dt)
{
    int i = blockIdx.x * 256 + threadIdx.x;       // BL*512 total
    int d = i & (DINNER - 1);
    size_t row = (size_t)i >> 9;
    const float* xr = dtBC + row * 48;
    const float* wr = Wdt + (size_t)d * DTRANK;
    float s = bdt[d];
    #pragma unroll
    for (int k = 0; k < DTRANK; ++k) s = fmaf(xr[k], wr[k], s);
    dt[i] = (s > 20.f) ? s : log1pf(expf(s));
}

// ---------------------------------------------------------------------------
// Chunked scan. Thread = one d channel; 16 states in registers.
// Pass 1: per-chunk zero-init run -> P (prod dA), q (end state).
// Layout: P/q/h0 [b][dir][c][n][d]  (d fastest -> coalesced)
// ---------------------------------------------------------------------------
__global__ void scan_pass1(const float* __restrict__ dtb,    // [B,L,512]
                           const float* __restrict__ x,      // [B,L,512] silu'd
                           const float* __restrict__ dtBC,   // [B,L,48]
                           const float* __restrict__ AlogF,
                           const float* __restrict__ AlogB,
                           float* __restrict__ Pbuf,
                           float* __restrict__ Qbuf)
{
    int b = blockIdx.z, dir = blockIdx.y;
    int c = blockIdx.x >> 2, dgrp = blockIdx.x & 3;
    int d = dgrp * 128 + threadIdx.x;
    const float* Alog = dir ? AlogB : AlogF;
    float a[DSTATE];
    #pragma unroll
    for (int n = 0; n < DSTATE; ++n) a[n] = -__expf(Alog[d * DSTATE + n]);
    float h[DSTATE], P[DSTATE];
    #pragma unroll
    for (int n = 0; n < DSTATE; ++n) { h[n] = 0.f; P[n] = 1.f; }

    for (int il = 0; il < LC; ++il) {
        int i = c * LC + il;
        int l = dir ? (LL - 1 - i) : i;
        size_t base = (size_t)b * LL + l;
        float dtv = dtb[base * DINNER + d];
        float u = x[base * DINNER + d];
        float du = dtv * u;
        const f32x4* Brow = reinterpret_cast<const f32x4*>(dtBC + base * 48 + DTRANK);
        f32x4 Bq[4];
        #pragma unroll
        for (int j = 0; j < 4; ++j) Bq[j] = Brow[j];
        #pragma unroll
        for (int n = 0; n < DSTATE; ++n) {
            float dA = __expf(dtv * a[n]);
            h[n] = fmaf(dA, h[n], du * Bq[n >> 2][n & 3]);
            P[n] *= dA;
        }
    }
    size_t o = ((((size_t)b * 2 + dir) * NC + c) * DSTATE) * DINNER + d;
    #pragma unroll
    for (int n = 0; n < DSTATE; ++n) {
        Pbuf[o + (size_t)n * DINNER] = P[n];
        Qbuf[o + (size_t)n * DINNER] = h[n];
    }
}

// Pass 2: stitch chunk-initial states. One thread per (b,dir,n,d) = 65536.
__global__ void scan_stitch(const float* __restrict__ Pbuf,
                            const float* __restrict__ Qbuf,
                            float* __restrict__ H0buf)
{
    int idx = blockIdx.x * 256 + threadIdx.x;   // 65536
    int bd = idx >> 13;           // (b*2+dir)
    int rem = idx & 8191;         // n*512 + d
    float H = 0.f;
    for (int c = 0; c < NC; ++c) {
        size_t o = ((size_t)bd * NC + c) * 8192 + rem;
        H0buf[o] = H;
        H = fmaf(Pbuf[o], H, Qbuf[o]);
    }
}

// Pass 3: re-run chunk from true initial state, emit y and per-chunk mean partials.
// NOTE: zs is ALREADY silu'd -> multiply directly (the round-1..3 bug).
__global__ void scan_pass3(const float* __restrict__ dtb,
                           const float* __restrict__ x,
                           const float* __restrict__ dtBC,
                           const float* __restrict__ AlogF,
                           const float* __restrict__ AlogB,
                           const float* __restrict__ Df,
                           const float* __restrict__ Db,
                           const float* __restrict__ zs,
                           const float* __restrict__ H0buf,
                           float* __restrict__ ycat,       // [B,L,1024]
                           float* __restrict__ partial)    // [B,NC,1024]
{
    int b = blockIdx.z, dir = blockIdx.y;
    int c = blockIdx.x >> 2, dgrp = blockIdx.x & 3;
    int d = dgrp * 128 + threadIdx.x;
    const float* Alog = dir ? AlogB : AlogF;
    float a[DSTATE];
    #pragma unroll
    for (int n = 0; n < DSTATE; ++n) a[n] = -__expf(Alog[d * DSTATE + n]);
    float Dd = dir ? Db[d] : Df[d];
    size_t o = ((((size_t)b * 2 + dir) * NC + c) * DSTATE) * DINNER + d;
    float h[DSTATE];
    #pragma unroll
    for (int n = 0; n < DSTATE; ++n) h[n] = H0buf[o + (size_t)n * DINNER];
    float ysum = 0.f;

    for (int il = 0; il < LC; ++il) {
        int i = c * LC + il;
        int l = dir ? (LL - 1 - i) : i;
        size_t base = (size_t)b * LL + l;
        float dtv = dtb[base * DINNER + d];
        float u = x[base * DINNER + d];
        float du = dtv * u;
        const f32x4* Brow = reinterpret_cast<const f32x4*>(dtBC + base * 48 + DTRANK);
        const f32x4* Crow = reinterpret_cast<const f32x4*>(dtBC + base * 48 + DTRANK + DSTATE);
        f32x4 Bq[4], Cq[4];
        #pragma unroll
        for (int j = 0; j < 4; ++j) { Bq[j] = Brow[j]; Cq[j] = Crow[j]; }
        float p = 0.f;
        #pragma unroll
        for (int n = 0; n < DSTATE; ++n) {
            float dA = __expf(dtv * a[n]);
            h[n] = fmaf(dA, h[n], du * Bq[n >> 2][n & 3]);
            p = fmaf(h[n], Cq[n >> 2][n & 3], p);
        }
        float zg = zs[base * DINNER + d];
        float yv = (p + Dd * u) * zg;
        ycat[base * (2 * DINNER) + dir * DINNER + d] = yv;
        ysum += yv;
    }
    partial[((size_t)b * NC + c) * 1024 + dir * DINNER + d] = ysum;
}

// mean over chunks -> ymean[b,1024]
__global__ void mean2(const float* __restrict__ partial, float* __restrict__ ymean)
{
    int i = blockIdx.x * 256 + threadIdx.x;   // 4096
    int b = i >> 10, ch = i & 1023;
    float s = 0.f;
    for (int c = 0; c < NC; ++c) s += partial[((size_t)b * NC + c) * 1024 + ch];
    ymean[i] = s / (float)LL;
}

// gemv: one wave per (b,j); 4096 waves.
template<int SIG>
__global__ void gemv1024(const float* __restrict__ vin,
                         const float* __restrict__ W,
                         const float* __restrict__ bias,
                         float* __restrict__ vout)
{
    int wv = (blockIdx.x * blockDim.x + threadIdx.x) >> 6;
    int b = wv >> 10, j = wv & 1023;
    int lane = threadIdx.x & 63;
    const float* wr = W + (size_t)j * 1024;
    const float* vr = vin + (size_t)b * 1024;
    float s = 0.f;
    for (int k = lane; k < 1024; k += 64) s = fmaf(vr[k], wr[k], s);
    #pragma unroll
    for (int o = 32; o; o >>= 1) s += __shfl_xor(s, o);
    if (lane == 0) {
        s += bias[j];
        vout[wv] = SIG ? (1.f / (1.f + expf(-s))) : s;
    }
}

__global__ void scale_y(float* __restrict__ ycat, const float* __restrict__ g)
{
    size_t i = (size_t)blockIdx.x * 256 + threadIdx.x;
    if (i >= (size_t)BL * 1024) return;
    int ch = (int)(i & 1023);
    int b = (int)((i >> 10) / LL);
    ycat[i] = ycat[i] * g[b * 1024 + ch];
}

// ---------------------------------------------------------------------------
extern "C" void kernel_launch(void* const* d_in, const int* in_sizes, int n_in,
                              void* d_out, int out_size, void* d_ws, size_t ws_size,
                              hipStream_t stream)
{
    const float* hidden  = (const float*)d_in[0];
    const float* W_in    = (const float*)d_in[1];
    const float* W_xproj = (const float*)d_in[2];
    const float* W_dt    = (const float*)d_in[3];
    const float* b_dt    = (const float*)d_in[4];
    const float* A_log_f = (const float*)d_in[5];
    const float* A_log_b = (const float*)d_in[6];
    const float* D_f     = (const float*)d_in[7];
    const float* D_b     = (const float*)d_in[8];
    const float* W_glob  = (const float*)d_in[9];
    const float* b_glob  = (const float*)d_in[10];
    const float* W_gate  = (const float*)d_in[11];
    const float* b_gate  = (const float*)d_in[12];
    const float* W_out   = (const float*)d_in[13];
    float* out = (float*)d_out;

    // workspace layout (fp32), ~66 MB
    char* w = (char*)d_ws;
    float* x_silu = (float*)w; w += (size_t)BL * DINNER * 4;
    float* z_silu = (float*)w; w += (size_t)BL * DINNER * 4;
    float* dtBC   = (float*)w; w += (size_t)BL * 48 * 4;
    float* dtb    = (float*)w; w += (size_t)BL * DINNER * 4;
    float* ycat   = (float*)w; w += (size_t)BL * 2 * DINNER * 4;
    float* Pbuf   = (float*)w; w += (size_t)BB * 2 * NC * DSTATE * DINNER * 4;
    float* Qbuf   = (float*)w; w += (size_t)BB * 2 * NC * DSTATE * DINNER * 4;
    float* H0buf  = (float*)w; w += (size_t)BB * 2 * NC * DSTATE * DINNER * 4;
    float* partial= (float*)w; w += (size_t)BB * NC * 1024 * 4;
    float* ymean  = (float*)w; w += (size_t)BB * 1024 * 4;
    float* t1     = (float*)w; w += (size_t)BB * 1024 * 4;
    float* gbuf   = (float*)w; w += (size_t)BB * 1024 * 4;

    // 1) xz = hidden @ W_in^T, silu -> x_silu, z_silu
    {
        int tiles = (BL / 16) * ((2 * DINNER) / 16);   // 14400
        gemm_bt<0><<<dim3((tiles + 3) / 4), dim3(256), 0, stream>>>(
            hidden, W_in, x_silu, z_silu, BL, 2 * DINNER, DMODEL);
    }
    // 2) x_dbl = x_silu @ W_xproj^T -> dtBC [BL,48]
    {
        int tiles = (BL / 16) * (48 / 16);             // 675
        gemm_bt<1><<<dim3((tiles + 3) / 4), dim3(256), 0, stream>>>(
            x_silu, W_xproj, dtBC, nullptr, BL, 48, DINNER);
    }
    // 3) dt precompute
    dt_kernel<<<dim3(BL * DINNER / 256), dim3(256), 0, stream>>>(dtBC, W_dt, b_dt, dtb);
    // 4) chunked scan
    scan_pass1<<<dim3(NC * 4, 2, BB), dim3(128), 0, stream>>>(
        dtb, x_silu, dtBC, A_log_f, A_log_b, Pbuf, Qbuf);
    scan_stitch<<<dim3(256), dim3(256), 0, stream>>>(Pbuf, Qbuf, H0buf);
    scan_pass3<<<dim3(NC * 4, 2, BB), dim3(128), 0, stream>>>(
        dtb, x_silu, dtBC, A_log_f, A_log_b, D_f, D_b, z_silu, H0buf, ycat, partial);
    // 5) mean
    mean2<<<dim3(16), dim3(256), 0, stream>>>(partial, ymean);
    // 6) gating
    gemv1024<0><<<dim3(1024), dim3(256), 0, stream>>>(ymean, W_glob, b_glob, t1);
    gemv1024<1><<<dim3(1024), dim3(256), 0, stream>>>(t1, W_gate, b_gate, gbuf);
    // 7) y *= g
    scale_y<<<dim3(BL * 1024 / 256), dim3(256), 0, stream>>>(ycat, gbuf);
    // 8) out = y @ W_out^T
    {
        int tiles = (BL / 16) * (DMODEL / 16);         // 3600
        gemm_bt<1><<<dim3((tiles + 3) / 4), dim3(256), 0, stream>>>(
            ycat, W_out, out, nullptr, BL, DMODEL, 2 * DINNER);
    }
}

// Round 6
// 291.280 us; speedup vs baseline: 5.6421x; 1.0044x over previous
//
#include <hip/hip_runtime.h>
#include <hip/hip_bf16.h>

// Problem constants
#define BB 4
#define LL 900
#define DMODEL 256
#define DSTATE 16
#define DINNER 512
#define DTRANK 16
#define BL (BB*LL)          // 3600
#define NC 30               // scan chunks
#define LC 30               // steps per chunk; NC*LC == LL

typedef __bf16 bf16x8 __attribute__((ext_vector_type(8)));
typedef __bf16 bf16x4 __attribute__((ext_vector_type(4)));
typedef float f32x4 __attribute__((ext_vector_type(4)));

__device__ __forceinline__ float silu_f(float v) { return v / (1.f + expf(-v)); }

// ---------------------------------------------------------------------------
// One-time hi/lo split of the GEMM weight/input operands (v ~= hi + lo).
// hidden: 921600, W_in: 262144, W_xproj: 24576, W_out: 262144
// ---------------------------------------------------------------------------
#define N_HID  (BL*DMODEL)             // 921600
#define N_WIN  (2*DINNER*DMODEL)       // 262144
#define N_WXP  (48*DINNER)             // 24576
#define N_WOUT (DMODEL*2*DINNER)       // 262144
__global__ void split_inputs(const float* __restrict__ hidden, const float* __restrict__ Win,
                             const float* __restrict__ Wxp, const float* __restrict__ Wout,
                             __bf16* __restrict__ hh, __bf16* __restrict__ hl,
                             __bf16* __restrict__ wih, __bf16* __restrict__ wil,
                             __bf16* __restrict__ wxh, __bf16* __restrict__ wxl,
                             __bf16* __restrict__ woh, __bf16* __restrict__ wol)
{
    int idx = blockIdx.x * 256 + threadIdx.x;
    const float* src; __bf16 *oh, *ol; int off;
    if (idx < N_HID)                       { src = hidden; oh = hh;  ol = hl;  off = idx; }
    else if (idx < N_HID+N_WIN)            { src = Win;    oh = wih; ol = wil; off = idx - N_HID; }
    else if (idx < N_HID+N_WIN+N_WXP)      { src = Wxp;    oh = wxh; ol = wxl; off = idx - N_HID - N_WIN; }
    else if (idx < N_HID+N_WIN+N_WXP+N_WOUT){ src = Wout;  oh = woh; ol = wol; off = idx - N_HID - N_WIN - N_WXP; }
    else return;
    float v = src[off];
    __bf16 h = (__bf16)v;
    oh[off] = h;
    ol[off] = (__bf16)(v - (float)h);
}

// ---------------------------------------------------------------------------
// Tiled MFMA GEMM on pre-split hi/lo bf16 operands.
// C[M,N] = A[M,K] @ B[N,K]^T, fp32 accum, 3 MFMA per 16x16x32 chunk (hh+hl+lh).
// Wave tile: (16*WM) x (16*WN). Block = 4 waves.
// MODE 0: silu epilogue; cols <512 -> hi/lo bf16 (outh/outl), cols >=512 -> fp32 out1
// MODE 1: plain fp32 store to out0 (ld = N)
// ---------------------------------------------------------------------------
template<int WM, int WN, int MODE>
__launch_bounds__(256)
__global__ void gemm_tiled(const __bf16* __restrict__ Ah, const __bf16* __restrict__ Al,
                           const __bf16* __restrict__ Bh, const __bf16* __restrict__ Bl,
                           float* __restrict__ out0, float* __restrict__ out1,
                           __bf16* __restrict__ outh, __bf16* __restrict__ outl,
                           int M, int N, int K)
{
    int wave = (blockIdx.x * 256 + threadIdx.x) >> 6;
    int ntM = M / (16 * WM), ntN = N / (16 * WN);
    if (wave >= ntM * ntN) return;
    int tm = wave / ntN, tn = wave % ntN;
    int lane = threadIdx.x & 63, q = lane >> 4, r = lane & 15;

    const bf16x8* ArH[WM]; const bf16x8* ArL[WM];
    const bf16x8* BrH[WN]; const bf16x8* BrL[WN];
    #pragma unroll
    for (int mi = 0; mi < WM; ++mi) {
        size_t row = (size_t)(tm * 16 * WM + mi * 16 + r) * K;
        ArH[mi] = reinterpret_cast<const bf16x8*>(Ah + row);
        ArL[mi] = reinterpret_cast<const bf16x8*>(Al + row);
    }
    #pragma unroll
    for (int ni = 0; ni < WN; ++ni) {
        size_t row = (size_t)(tn * 16 * WN + ni * 16 + r) * K;
        BrH[ni] = reinterpret_cast<const bf16x8*>(Bh + row);
        BrL[ni] = reinterpret_cast<const bf16x8*>(Bl + row);
    }

    f32x4 acc[WM][WN];
    #pragma unroll
    for (int mi = 0; mi < WM; ++mi)
        #pragma unroll
        for (int ni = 0; ni < WN; ++ni) acc[mi][ni] = (f32x4){0.f,0.f,0.f,0.f};

    int nk = K >> 5;
    for (int kk = 0; kk < nk; ++kk) {
        int idx = kk * 4 + q;
        bf16x8 a_h[WM], a_l[WM], b_h[WN], b_l[WN];
        #pragma unroll
        for (int mi = 0; mi < WM; ++mi) { a_h[mi] = ArH[mi][idx]; a_l[mi] = ArL[mi][idx]; }
        #pragma unroll
        for (int ni = 0; ni < WN; ++ni) { b_h[ni] = BrH[ni][idx]; b_l[ni] = BrL[ni][idx]; }
        #pragma unroll
        for (int mi = 0; mi < WM; ++mi)
            #pragma unroll
            for (int ni = 0; ni < WN; ++ni) {
                acc[mi][ni] = __builtin_amdgcn_mfma_f32_16x16x32_bf16(a_h[mi], b_h[ni], acc[mi][ni], 0, 0, 0);
                acc[mi][ni] = __builtin_amdgcn_mfma_f32_16x16x32_bf16(a_h[mi], b_l[ni], acc[mi][ni], 0, 0, 0);
                acc[mi][ni] = __builtin_amdgcn_mfma_f32_16x16x32_bf16(a_l[mi], b_h[ni], acc[mi][ni], 0, 0, 0);
            }
    }

    #pragma unroll
    for (int mi = 0; mi < WM; ++mi)
        #pragma unroll
        for (int ni = 0; ni < WN; ++ni) {
            int col = tn * 16 * WN + ni * 16 + r;
            #pragma unroll
            for (int i = 0; i < 4; ++i) {
                int row = tm * 16 * WM + mi * 16 + q * 4 + i;
                float v = acc[mi][ni][i];
                if (MODE == 0) {
                    float s = silu_f(v);
                    if (col < DINNER) {
                        __bf16 h = (__bf16)s;
                        outh[(size_t)row * DINNER + col] = h;
                        outl[(size_t)row * DINNER + col] = (__bf16)(s - (float)h);
                    } else {
                        out1[(size_t)row * DINNER + (col - DINNER)] = s;
                    }
                } else {
                    out0[(size_t)row * N + col] = v;
                }
            }
        }
}

// ---------------------------------------------------------------------------
// Chunked scan pass 1 (zero-init run per chunk) with dt computed inline.
// Thread = one d channel. Layout P/Q/H0: [b][dir][c][n][d] (d fastest).
// ---------------------------------------------------------------------------
__global__ void scan_pass1(const __bf16* __restrict__ xh, const __bf16* __restrict__ xl,
                           const float* __restrict__ dtBC,   // [B,L,48]
                           const float* __restrict__ Wdt, const float* __restrict__ bdt,
                           const float* __restrict__ AlogF, const float* __restrict__ AlogB,
                           float* __restrict__ Pbuf, float* __restrict__ Qbuf)
{
    int b = blockIdx.z, dir = blockIdx.y;
    int c = blockIdx.x >> 2, dgrp = blockIdx.x & 3;
    int d = dgrp * 128 + threadIdx.x;
    const float* Alog = dir ? AlogB : AlogF;
    float a[DSTATE];
    #pragma unroll
    for (int n = 0; n < DSTATE; ++n) a[n] = -__expf(Alog[d * DSTATE + n]);
    float wreg[DTRANK];
    const float* wr = Wdt + (size_t)d * DTRANK;
    #pragma unroll
    for (int k = 0; k < DTRANK; ++k) wreg[k] = wr[k];
    float bd = bdt[d];
    float h[DSTATE], P[DSTATE];
    #pragma unroll
    for (int n = 0; n < DSTATE; ++n) { h[n] = 0.f; P[n] = 1.f; }

    for (int il = 0; il < LC; ++il) {
        int i = c * LC + il;
        int l = dir ? (LL - 1 - i) : i;
        size_t base = (size_t)b * LL + l;
        const f32x4* xq = reinterpret_cast<const f32x4*>(dtBC + base * 48);
        f32x4 dq[4], Bq[4];
        #pragma unroll
        for (int j = 0; j < 4; ++j) dq[j] = xq[j];
        #pragma unroll
        for (int j = 0; j < 4; ++j) Bq[j] = xq[4 + j];
        float s = bd;
        #pragma unroll
        for (int j = 0; j < 4; ++j)
            #pragma unroll
            for (int e = 0; e < 4; ++e) s = fmaf(dq[j][e], wreg[4 * j + e], s);
        float dtv = (s > 20.f) ? s : log1pf(expf(s));
        float u = (float)xh[base * DINNER + d] + (float)xl[base * DINNER + d];
        float du = dtv * u;
        #pragma unroll
        for (int n = 0; n < DSTATE; ++n) {
            float dA = __expf(dtv * a[n]);
            h[n] = fmaf(dA, h[n], du * Bq[n >> 2][n & 3]);
            P[n] *= dA;
        }
    }
    size_t o = ((((size_t)b * 2 + dir) * NC + c) * DSTATE) * DINNER + d;
    #pragma unroll
    for (int n = 0; n < DSTATE; ++n) {
        Pbuf[o + (size_t)n * DINNER] = P[n];
        Qbuf[o + (size_t)n * DINNER] = h[n];
    }
}

// Pass 2: stitch chunk-initial states. One thread per (b,dir,n,d) = 65536.
__global__ void scan_stitch(const float* __restrict__ Pbuf,
                            const float* __restrict__ Qbuf,
                            float* __restrict__ H0buf)
{
    int idx = blockIdx.x * 256 + threadIdx.x;   // 65536
    int bd = idx >> 13;           // (b*2+dir)
    int rem = idx & 8191;         // n*512 + d
    float H = 0.f;
    for (int c = 0; c < NC; ++c) {
        size_t o = ((size_t)bd * NC + c) * 8192 + rem;
        H0buf[o] = H;
        H = fmaf(Pbuf[o], H, Qbuf[o]);
    }
}

// Pass 3: re-run chunk from true initial state; emit y (hi/lo bf16) + mean partials.
// zs (z_silu) is ALREADY silu'd -> multiply directly.
__global__ void scan_pass3(const __bf16* __restrict__ xh, const __bf16* __restrict__ xl,
                           const float* __restrict__ dtBC,
                           const float* __restrict__ Wdt, const float* __restrict__ bdt,
                           const float* __restrict__ AlogF, const float* __restrict__ AlogB,
                           const float* __restrict__ Df, const float* __restrict__ Db,
                           const float* __restrict__ zs,
                           const float* __restrict__ H0buf,
                           __bf16* __restrict__ yh, __bf16* __restrict__ yl,  // [B,L,1024]
                           float* __restrict__ partial)                       // [B,NC,1024]
{
    int b = blockIdx.z, dir = blockIdx.y;
    int c = blockIdx.x >> 2, dgrp = blockIdx.x & 3;
    int d = dgrp * 128 + threadIdx.x;
    const float* Alog = dir ? AlogB : AlogF;
    float a[DSTATE];
    #pragma unroll
    for (int n = 0; n < DSTATE; ++n) a[n] = -__expf(Alog[d * DSTATE + n]);
    float wreg[DTRANK];
    const float* wr = Wdt + (size_t)d * DTRANK;
    #pragma unroll
    for (int k = 0; k < DTRANK; ++k) wreg[k] = wr[k];
    float bd2 = bdt[d];
    float Dd = dir ? Db[d] : Df[d];
    size_t o = ((((size_t)b * 2 + dir) * NC + c) * DSTATE) * DINNER + d;
    float h[DSTATE];
    #pragma unroll
    for (int n = 0; n < DSTATE; ++n) h[n] = H0buf[o + (size_t)n * DINNER];
    float ysum = 0.f;

    for (int il = 0; il < LC; ++il) {
        int i = c * LC + il;
        int l = dir ? (LL - 1 - i) : i;
        size_t base = (size_t)b * LL + l;
        const f32x4* xq = reinterpret_cast<const f32x4*>(dtBC + base * 48);
        f32x4 dq[4], Bq[4], Cq[4];
        #pragma unroll
        for (int j = 0; j < 4; ++j) dq[j] = xq[j];
        #pragma unroll
        for (int j = 0; j < 4; ++j) Bq[j] = xq[4 + j];
        #pragma unroll
        for (int j = 0; j < 4; ++j) Cq[j] = xq[8 + j];
        float s = bd2;
        #pragma unroll
        for (int j = 0; j < 4; ++j)
            #pragma unroll
            for (int e = 0; e < 4; ++e) s = fmaf(dq[j][e], wreg[4 * j + e], s);
        float dtv = (s > 20.f) ? s : log1pf(expf(s));
        float u = (float)xh[base * DINNER + d] + (float)xl[base * DINNER + d];
        float du = dtv * u;
        float p = 0.f;
        #pragma unroll
        for (int n = 0; n < DSTATE; ++n) {
            float dA = __expf(dtv * a[n]);
            h[n] = fmaf(dA, h[n], du * Bq[n >> 2][n & 3]);
            p = fmaf(h[n], Cq[n >> 2][n & 3], p);
        }
        float zg = zs[base * DINNER + d];
        float yv = (p + Dd * u) * zg;
        __bf16 hv = (__bf16)yv;
        size_t yo = base * (2 * DINNER) + dir * DINNER + d;
        yh[yo] = hv;
        yl[yo] = (__bf16)(yv - (float)hv);
        ysum += yv;
    }
    partial[((size_t)b * NC + c) * 1024 + dir * DINNER + d] = ysum;
}

// mean over chunks -> ymean[b,1024]
__global__ void mean2(const float* __restrict__ partial, float* __restrict__ ymean)
{
    int i = blockIdx.x * 256 + threadIdx.x;   // 4096
    int b = i >> 10, ch = i & 1023;
    float s = 0.f;
    for (int c = 0; c < NC; ++c) s += partial[((size_t)b * NC + c) * 1024 + ch];
    ymean[i] = s / (float)LL;
}

// gemv: one wave per (b,j); 4096 waves.
template<int SIG>
__global__ void gemv1024(const float* __restrict__ vin,
                         const float* __restrict__ W,
                         const float* __restrict__ bias,
                         float* __restrict__ vout)
{
    int wv = (blockIdx.x * blockDim.x + threadIdx.x) >> 6;
    int b = wv >> 10, j = wv & 1023;
    int lane = threadIdx.x & 63;
    const float* wr = W + (size_t)j * 1024;
    const float* vr = vin + (size_t)b * 1024;
    float s = 0.f;
    for (int k = lane; k < 1024; k += 64) s = fmaf(vr[k], wr[k], s);
    #pragma unroll
    for (int o = 32; o; o >>= 1) s += __shfl_xor(s, o);
    if (lane == 0) {
        s += bias[j];
        vout[wv] = SIG ? (1.f / (1.f + expf(-s))) : s;
    }
}

// y(hi/lo) *= g[b,ch], in place, 4 elems/thread
__global__ void scale_split(__bf16* __restrict__ yh, __bf16* __restrict__ yl,
                            const float* __restrict__ g)
{
    int idx = blockIdx.x * 256 + threadIdx.x;   // BL*1024/4 = 921600
    int e = idx * 4;
    int ch = e & 1023;
    int b = (e >> 10) / LL;
    bf16x4 hv = reinterpret_cast<bf16x4*>(yh)[idx];
    bf16x4 lv = reinterpret_cast<bf16x4*>(yl)[idx];
    f32x4 gv = *reinterpret_cast<const f32x4*>(g + b * 1024 + ch);
    #pragma unroll
    for (int j = 0; j < 4; ++j) {
        float v = ((float)hv[j] + (float)lv[j]) * gv[j];
        __bf16 h = (__bf16)v;
        hv[j] = h;
        lv[j] = (__bf16)(v - (float)h);
    }
    reinterpret_cast<bf16x4*>(yh)[idx] = hv;
    reinterpret_cast<bf16x4*>(yl)[idx] = lv;
}

// ---------------------------------------------------------------------------
extern "C" void kernel_launch(void* const* d_in, const int* in_sizes, int n_in,
                              void* d_out, int out_size, void* d_ws, size_t ws_size,
                              hipStream_t stream)
{
    const float* hidden  = (const float*)d_in[0];
    const float* W_in    = (const float*)d_in[1];
    const float* W_xproj = (const float*)d_in[2];
    const float* W_dt    = (const float*)d_in[3];
    const float* b_dt    = (const float*)d_in[4];
    const float* A_log_f = (const float*)d_in[5];
    const float* A_log_b = (const float*)d_in[6];
    const float* D_f     = (const float*)d_in[7];
    const float* D_b     = (const float*)d_in[8];
    const float* W_glob  = (const float*)d_in[9];
    const float* b_glob  = (const float*)d_in[10];
    const float* W_gate  = (const float*)d_in[11];
    const float* b_gate  = (const float*)d_in[12];
    const float* W_out   = (const float*)d_in[13];
    float* out = (float*)d_out;

    // workspace layout (~60 MB)
    char* w = (char*)d_ws;
    __bf16* xh    = (__bf16*)w; w += (size_t)BL * DINNER * 2;            // 3.69 MB
    __bf16* xl    = (__bf16*)w; w += (size_t)BL * DINNER * 2;            // 3.69 MB
    float* z_silu = (float*)w;  w += (size_t)BL * DINNER * 4;            // 7.37 MB
    float* dtBC   = (float*)w;  w += (size_t)BL * 48 * 4;                // 0.69 MB
    __bf16* yh    = (__bf16*)w; w += (size_t)BL * 2 * DINNER * 2;        // 7.37 MB
    __bf16* yl    = (__bf16*)w; w += (size_t)BL * 2 * DINNER * 2;        // 7.37 MB
    float* Pbuf   = (float*)w;  w += (size_t)BB * 2 * NC * DSTATE * DINNER * 4;  // 7.86 MB
    float* Qbuf   = (float*)w;  w += (size_t)BB * 2 * NC * DSTATE * DINNER * 4;  // 7.86 MB
    float* H0buf  = (float*)w;  w += (size_t)BB * 2 * NC * DSTATE * DINNER * 4;  // 7.86 MB
    float* partial= (float*)w;  w += (size_t)BB * NC * 1024 * 4;         // 0.49 MB
    float* ymean  = (float*)w;  w += (size_t)BB * 1024 * 4;
    float* t1     = (float*)w;  w += (size_t)BB * 1024 * 4;
    float* gbuf   = (float*)w;  w += (size_t)BB * 1024 * 4;
    __bf16* hh    = (__bf16*)w; w += (size_t)N_HID * 2;                  // 1.84 MB
    __bf16* hl    = (__bf16*)w; w += (size_t)N_HID * 2;
    __bf16* wih   = (__bf16*)w; w += (size_t)N_WIN * 2;                  // 0.52 MB
    __bf16* wil   = (__bf16*)w; w += (size_t)N_WIN * 2;
    __bf16* wxh   = (__bf16*)w; w += (size_t)N_WXP * 2;
    __bf16* wxl   = (__bf16*)w; w += (size_t)N_WXP * 2;
    __bf16* woh   = (__bf16*)w; w += (size_t)N_WOUT * 2;
    __bf16* wol   = (__bf16*)w; w += (size_t)N_WOUT * 2;

    // 0) hi/lo split of hidden + weights
    {
        int tot = N_HID + N_WIN + N_WXP + N_WOUT;
        split_inputs<<<dim3((tot + 255) / 256), dim3(256), 0, stream>>>(
            hidden, W_in, W_xproj, W_out, hh, hl, wih, wil, wxh, wxl, woh, wol);
    }
    // 1) xz = hidden @ W_in^T; silu; x -> (xh,xl), z -> z_silu
    {
        int waves = (BL / 48) * ((2 * DINNER) / 64);   // 75*16 = 1200
        gemm_tiled<3, 4, 0><<<dim3((waves + 3) / 4), dim3(256), 0, stream>>>(
            hh, hl, wih, wil, nullptr, z_silu, xh, xl, BL, 2 * DINNER, DMODEL);
    }
    // 2) x_dbl = x @ W_xproj^T -> dtBC [BL,48]
    {
        int waves = (BL / 16) * (48 / 48);             // 225
        gemm_tiled<1, 3, 1><<<dim3((waves + 3) / 4), dim3(256), 0, stream>>>(
            xh, xl, wxh, wxl, dtBC, nullptr, nullptr, nullptr, BL, 48, DINNER);
    }
    // 3) chunked scan (dt inline)
    scan_pass1<<<dim3(NC * 4, 2, BB), dim3(128), 0, stream>>>(
        xh, xl, dtBC, W_dt, b_dt, A_log_f, A_log_b, Pbuf, Qbuf);
    scan_stitch<<<dim3(256), dim3(256), 0, stream>>>(Pbuf, Qbuf, H0buf);
    scan_pass3<<<dim3(NC * 4, 2, BB), dim3(128), 0, stream>>>(
        xh, xl, dtBC, W_dt, b_dt, A_log_f, A_log_b, D_f, D_b, z_silu, H0buf, yh, yl, partial);
    // 4) mean
    mean2<<<dim3(16), dim3(256), 0, stream>>>(partial, ymean);
    // 5) gating
    gemv1024<0><<<dim3(1024), dim3(256), 0, stream>>>(ymean, W_glob, b_glob, t1);
    gemv1024<1><<<dim3(1024), dim3(256), 0, stream>>>(t1, W_gate, b_gate, gbuf);
    // 6) y *= g (in place on hi/lo)
    scale_split<<<dim3(BL * 1024 / 4 / 256), dim3(256), 0, stream>>>(yh, yl, gbuf);
    // 7) out = y @ W_out^T (fp32 out)
    {
        int waves = (BL / 48) * (DMODEL / 32);         // 75*8 = 600
        gemm_tiled<3, 2, 1><<<dim3((waves + 3) / 4), dim3(256), 0, stream>>>(
            yh, yl, woh, wol, out, nullptr, nullptr, nullptr, BL, DMODEL, 2 * DINNER);
    }
}

// Round 7
// 275.213 us; speedup vs baseline: 5.9715x; 1.0584x over previous
//
#include <hip/hip_runtime.h>
#include <hip/hip_bf16.h>

// Problem constants
#define BB 4
#define LL 900
#define DMODEL 256
#define DSTATE 16
#define DINNER 512
#define DTRANK 16
#define BL (BB*LL)          // 3600
#define NC 50               // scan chunks
#define LC 18               // steps per chunk; NC*LC == LL

typedef __bf16 bf16x8 __attribute__((ext_vector_type(8)));
typedef __bf16 bf16x4 __attribute__((ext_vector_type(4)));
typedef float f32x4 __attribute__((ext_vector_type(4)));

__device__ __forceinline__ float silu_f(float v) { return v / (1.f + __expf(-v)); }

// ---------------------------------------------------------------------------
// One-time hi/lo split of GEMM operands (v ~= hi + lo)
// ---------------------------------------------------------------------------
#define N_HID  (BL*DMODEL)             // 921600
#define N_WIN  (2*DINNER*DMODEL)       // 262144
#define N_WXP  (48*DINNER)             // 24576
#define N_WOUT (DMODEL*2*DINNER)       // 262144
__global__ void split_inputs(const float* __restrict__ hidden, const float* __restrict__ Win,
                             const float* __restrict__ Wxp, const float* __restrict__ Wout,
                             __bf16* __restrict__ hh, __bf16* __restrict__ hl,
                             __bf16* __restrict__ wih, __bf16* __restrict__ wil,
                             __bf16* __restrict__ wxh, __bf16* __restrict__ wxl,
                             __bf16* __restrict__ woh, __bf16* __restrict__ wol)
{
    int idx = blockIdx.x * 256 + threadIdx.x;
    const float* src; __bf16 *oh, *ol; int off;
    if (idx < N_HID)                       { src = hidden; oh = hh;  ol = hl;  off = idx; }
    else if (idx < N_HID+N_WIN)            { src = Win;    oh = wih; ol = wil; off = idx - N_HID; }
    else if (idx < N_HID+N_WIN+N_WXP)      { src = Wxp;    oh = wxh; ol = wxl; off = idx - N_HID - N_WIN; }
    else if (idx < N_HID+N_WIN+N_WXP+N_WOUT){ src = Wout;  oh = woh; ol = wol; off = idx - N_HID - N_WIN - N_WXP; }
    else return;
    float v = src[off];
    __bf16 h = (__bf16)v;
    oh[off] = h;
    ol[off] = (__bf16)(v - (float)h);
}

// ---------------------------------------------------------------------------
// Tiled MFMA GEMM on pre-split hi/lo bf16, with optional K-split (KS slices).
// C[M,N] = A[M,K] @ B[N,K]^T, fp32 accum, 3 MFMA per 16x16x32 chunk.
// MODE 0: silu epilogue (KS must be 1); cols<512 -> hi/lo bf16, else fp32 out1
// MODE 1: fp32 store to out0 + ks*M*N (partial per K-slice)
// ---------------------------------------------------------------------------
template<int WM, int WN, int MODE, int KS>
__launch_bounds__(256)
__global__ void gemm_tiled(const __bf16* __restrict__ Ah, const __bf16* __restrict__ Al,
                           const __bf16* __restrict__ Bh, const __bf16* __restrict__ Bl,
                           float* __restrict__ out0, float* __restrict__ out1,
                           __bf16* __restrict__ outh, __bf16* __restrict__ outl,
                           int M, int N, int K)
{
    int wave = (blockIdx.x * 256 + threadIdx.x) >> 6;
    int ntM = M / (16 * WM), ntN = N / (16 * WN);
    int tilesPer = ntM * ntN;
    if (wave >= tilesPer * KS) return;
    int ks = wave / tilesPer, t = wave % tilesPer;
    int tm = t / ntN, tn = t % ntN;
    int kOff = ks * (K / KS);
    int nk = (K / KS) >> 5;
    int lane = threadIdx.x & 63, q = lane >> 4, r = lane & 15;

    const bf16x8* ArH[WM]; const bf16x8* ArL[WM];
    const bf16x8* BrH[WN]; const bf16x8* BrL[WN];
    #pragma unroll
    for (int mi = 0; mi < WM; ++mi) {
        size_t row = (size_t)(tm * 16 * WM + mi * 16 + r) * K + kOff;
        ArH[mi] = reinterpret_cast<const bf16x8*>(Ah + row);
        ArL[mi] = reinterpret_cast<const bf16x8*>(Al + row);
    }
    #pragma unroll
    for (int ni = 0; ni < WN; ++ni) {
        size_t row = (size_t)(tn * 16 * WN + ni * 16 + r) * K + kOff;
        BrH[ni] = reinterpret_cast<const bf16x8*>(Bh + row);
        BrL[ni] = reinterpret_cast<const bf16x8*>(Bl + row);
    }

    f32x4 acc[WM][WN];
    #pragma unroll
    for (int mi = 0; mi < WM; ++mi)
        #pragma unroll
        for (int ni = 0; ni < WN; ++ni) acc[mi][ni] = (f32x4){0.f,0.f,0.f,0.f};

    #pragma unroll 2
    for (int kk = 0; kk < nk; ++kk) {
        int idx = kk * 4 + q;
        bf16x8 a_h[WM], a_l[WM], b_h[WN], b_l[WN];
        #pragma unroll
        for (int mi = 0; mi < WM; ++mi) { a_h[mi] = ArH[mi][idx]; a_l[mi] = ArL[mi][idx]; }
        #pragma unroll
        for (int ni = 0; ni < WN; ++ni) { b_h[ni] = BrH[ni][idx]; b_l[ni] = BrL[ni][idx]; }
        #pragma unroll
        for (int mi = 0; mi < WM; ++mi)
            #pragma unroll
            for (int ni = 0; ni < WN; ++ni) {
                acc[mi][ni] = __builtin_amdgcn_mfma_f32_16x16x32_bf16(a_h[mi], b_h[ni], acc[mi][ni], 0, 0, 0);
                acc[mi][ni] = __builtin_amdgcn_mfma_f32_16x16x32_bf16(a_h[mi], b_l[ni], acc[mi][ni], 0, 0, 0);
                acc[mi][ni] = __builtin_amdgcn_mfma_f32_16x16x32_bf16(a_l[mi], b_h[ni], acc[mi][ni], 0, 0, 0);
            }
    }

    float* o0 = out0 + (size_t)ks * M * N;
    #pragma unroll
    for (int mi = 0; mi < WM; ++mi)
        #pragma unroll
        for (int ni = 0; ni < WN; ++ni) {
            int col = tn * 16 * WN + ni * 16 + r;
            #pragma unroll
            for (int i = 0; i < 4; ++i) {
                int row = tm * 16 * WM + mi * 16 + q * 4 + i;
                float v = acc[mi][ni][i];
                if (MODE == 0) {
                    float s = silu_f(v);
                    if (col < DINNER) {
                        __bf16 h = (__bf16)s;
                        outh[(size_t)row * DINNER + col] = h;
                        outl[(size_t)row * DINNER + col] = (__bf16)(s - (float)h);
                    } else {
                        out1[(size_t)row * DINNER + (col - DINNER)] = s;
                    }
                } else {
                    o0[(size_t)row * N + col] = v;
                }
            }
        }
}

// combine K-split partials: out[i] = sum_p in[p*n + i]
template<int P>
__global__ void combineP(const float* __restrict__ in, float* __restrict__ out, int n)
{
    int i = blockIdx.x * 256 + threadIdx.x;
    if (i >= n) return;
    float s = 0.f;
    #pragma unroll
    for (int p = 0; p < P; ++p) s += in[(size_t)p * n + i];
    out[i] = s;
}

// ---------------------------------------------------------------------------
// dt precompute: dtv = softplus(dtBC[:, :16] @ Wdt^T + bdt); also du = dtv*u.
// One thread per (row, d). Fully parallel (7200 blocks).
// ---------------------------------------------------------------------------
__global__ void dt_kernel(const float* __restrict__ dtBC,
                          const float* __restrict__ Wdt, const float* __restrict__ bdt,
                          const __bf16* __restrict__ xh, const __bf16* __restrict__ xl,
                          float* __restrict__ dtb, float* __restrict__ dub)
{
    int i = blockIdx.x * 256 + threadIdx.x;       // BL*512
    int d = i & (DINNER - 1);
    size_t row = (size_t)i >> 9;
    const float* xr = dtBC + row * 48;
    const float* wr = Wdt + (size_t)d * DTRANK;
    float s = bdt[d];
    #pragma unroll
    for (int k = 0; k < DTRANK; ++k) s = fmaf(xr[k], wr[k], s);
    float dtv = (s > 15.f) ? s : __logf(1.f + __expf(s));
    float u = (float)xh[i] + (float)xl[i];
    dtb[i] = dtv;
    dub[i] = dtv * u;
}

// ---------------------------------------------------------------------------
// Chunked scan pass 1: per-chunk zero-init run -> Q (end state), P = exp2(a2*Σdt).
// Layout P/Q: [b][dir][c][n][d] (d fastest).
// ---------------------------------------------------------------------------
__global__ void scan_pass1(const float* __restrict__ dtb, const float* __restrict__ dub,
                           const float* __restrict__ dtBC,
                           const float* __restrict__ AlogF, const float* __restrict__ AlogB,
                           float* __restrict__ Pbuf, float* __restrict__ Qbuf)
{
    int b = blockIdx.z, dir = blockIdx.y;
    int c = blockIdx.x >> 2, dgrp = blockIdx.x & 3;
    int d = dgrp * 128 + threadIdx.x;
    const float* Alog = dir ? AlogB : AlogF;
    float a2[DSTATE];
    #pragma unroll
    for (int n = 0; n < DSTATE; ++n) a2[n] = -__expf(Alog[d * DSTATE + n]) * 1.44269504f;
    float h[DSTATE];
    #pragma unroll
    for (int n = 0; n < DSTATE; ++n) h[n] = 0.f;
    float sdt = 0.f;

    #pragma unroll 2
    for (int il = 0; il < LC; ++il) {
        int i = c * LC + il;
        int l = dir ? (LL - 1 - i) : i;
        size_t base = (size_t)b * LL + l;
        float dtv = dtb[base * DINNER + d];
        float du  = dub[base * DINNER + d];
        const f32x4* Bp = reinterpret_cast<const f32x4*>(dtBC + base * 48 + DTRANK);
        f32x4 Bq[4];
        #pragma unroll
        for (int j = 0; j < 4; ++j) Bq[j] = Bp[j];
        sdt += dtv;
        #pragma unroll
        for (int n = 0; n < DSTATE; ++n)
            h[n] = fmaf(exp2f(dtv * a2[n]), h[n], du * Bq[n >> 2][n & 3]);
    }
    size_t o = (((size_t)(b * 2 + dir) * NC + c) * DSTATE) * DINNER + d;
    #pragma unroll
    for (int n = 0; n < DSTATE; ++n) {
        Pbuf[o + (size_t)n * DINNER] = exp2f(sdt * a2[n]);
        Qbuf[o + (size_t)n * DINNER] = h[n];
    }
}

// Pass 2: stitch chunk-initial states IN PLACE (H0 overwrites Pbuf).
__global__ void scan_stitch(float* __restrict__ Pbuf, const float* __restrict__ Qbuf)
{
    int idx = blockIdx.x * 256 + threadIdx.x;   // 65536
    int bd = idx >> 13;           // (b*2+dir)
    int rem = idx & 8191;         // n*512 + d
    float H = 0.f;
    for (int c = 0; c < NC; ++c) {
        size_t o = ((size_t)bd * NC + c) * 8192 + rem;
        float Pv = Pbuf[o], Qv = Qbuf[o];
        Pbuf[o] = H;              // store chunk-initial state
        H = fmaf(Pv, H, Qv);
    }
}

// Pass 3: re-run chunk from true initial state (read from Pbuf); emit y hi/lo + partials.
// zs (z_silu) is ALREADY silu'd.
__global__ void scan_pass3(const float* __restrict__ dtb, const float* __restrict__ dub,
                           const __bf16* __restrict__ xh, const __bf16* __restrict__ xl,
                           const float* __restrict__ dtBC,
                           const float* __restrict__ AlogF, const float* __restrict__ AlogB,
                           const float* __restrict__ Df, const float* __restrict__ Db,
                           const float* __restrict__ zs,
                           const float* __restrict__ H0buf,
                           __bf16* __restrict__ yh, __bf16* __restrict__ yl,  // [B,L,1024]
                           float* __restrict__ partial)                       // [B,NC,1024]
{
    int b = blockIdx.z, dir = blockIdx.y;
    int c = blockIdx.x >> 2, dgrp = blockIdx.x & 3;
    int d = dgrp * 128 + threadIdx.x;
    const float* Alog = dir ? AlogB : AlogF;
    float a2[DSTATE];
    #pragma unroll
    for (int n = 0; n < DSTATE; ++n) a2[n] = -__expf(Alog[d * DSTATE + n]) * 1.44269504f;
    float Dd = dir ? Db[d] : Df[d];
    size_t o = (((size_t)(b * 2 + dir) * NC + c) * DSTATE) * DINNER + d;
    float h[DSTATE];
    #pragma unroll
    for (int n = 0; n < DSTATE; ++n) h[n] = H0buf[o + (size_t)n * DINNER];
    float ysum = 0.f;

    #pragma unroll 2
    for (int il = 0; il < LC; ++il) {
        int i = c * LC + il;
        int l = dir ? (LL - 1 - i) : i;
        size_t base = (size_t)b * LL + l;
        float dtv = dtb[base * DINNER + d];
        float du  = dub[base * DINNER + d];
        const f32x4* Bp = reinterpret_cast<const f32x4*>(dtBC + base * 48 + DTRANK);
        f32x4 Bq[4], Cq[4];
        #pragma unroll
        for (int j = 0; j < 4; ++j) Bq[j] = Bp[j];
        #pragma unroll
        for (int j = 0; j < 4; ++j) Cq[j] = Bp[4 + j];
        float p = 0.f;
        #pragma unroll
        for (int n = 0; n < DSTATE; ++n) {
            h[n] = fmaf(exp2f(dtv * a2[n]), h[n], du * Bq[n >> 2][n & 3]);
            p = fmaf(h[n], Cq[n >> 2][n & 3], p);
        }
        float u = (float)xh[base * DINNER + d] + (float)xl[base * DINNER + d];
        float zg = zs[base * DINNER + d];
        float yv = (p + Dd * u) * zg;
        __bf16 hv = (__bf16)yv;
        size_t yo = base * (2 * DINNER) + dir * DINNER + d;
        yh[yo] = hv;
        yl[yo] = (__bf16)(yv - (float)hv);
        ysum += yv;
    }
    partial[((size_t)b * NC + c) * 1024 + dir * DINNER + d] = ysum;
}

// mean over chunks -> ymean[b,1024]
__global__ void mean2(const float* __restrict__ partial, float* __restrict__ ymean)
{
    int i = blockIdx.x * 256 + threadIdx.x;   // 4096
    int b = i >> 10, ch = i & 1023;
    float s = 0.f;
    for (int c = 0; c < NC; ++c) s += partial[((size_t)b * NC + c) * 1024 + ch];
    ymean[i] = s / (float)LL;
}

// gemv: one wave per (b,j); 4096 waves.
template<int SIG>
__global__ void gemv1024(const float* __restrict__ vin,
                         const float* __restrict__ W,
                         const float* __restrict__ bias,
                         float* __restrict__ vout)
{
    int wv = (blockIdx.x * blockDim.x + threadIdx.x) >> 6;
    int b = wv >> 10, j = wv & 1023;
    int lane = threadIdx.x & 63;
    const float* wr = W + (size_t)j * 1024;
    const float* vr = vin + (size_t)b * 1024;
    float s = 0.f;
    for (int k = lane; k < 1024; k += 64) s = fmaf(vr[k], wr[k], s);
    #pragma unroll
    for (int o = 32; o; o >>= 1) s += __shfl_xor(s, o);
    if (lane == 0) {
        s += bias[j];
        vout[wv] = SIG ? (1.f / (1.f + __expf(-s))) : s;
    }
}

// y(hi/lo) *= g[b,ch], in place, 4 elems/thread
__global__ void scale_split(__bf16* __restrict__ yh, __bf16* __restrict__ yl,
                            const float* __restrict__ g)
{
    int idx = blockIdx.x * 256 + threadIdx.x;   // BL*1024/4
    int e = idx * 4;
    int ch = e & 1023;
    int b = (e >> 10) / LL;
    bf16x4 hv = reinterpret_cast<bf16x4*>(yh)[idx];
    bf16x4 lv = reinterpret_cast<bf16x4*>(yl)[idx];
    f32x4 gv = *reinterpret_cast<const f32x4*>(g + b * 1024 + ch);
    #pragma unroll
    for (int j = 0; j < 4; ++j) {
        float v = ((float)hv[j] + (float)lv[j]) * gv[j];
        __bf16 h = (__bf16)v;
        hv[j] = h;
        lv[j] = (__bf16)(v - (float)h);
    }
    reinterpret_cast<bf16x4*>(yh)[idx] = hv;
    reinterpret_cast<bf16x4*>(yl)[idx] = lv;
}

// ---------------------------------------------------------------------------
extern "C" void kernel_launch(void* const* d_in, const int* in_sizes, int n_in,
                              void* d_out, int out_size, void* d_ws, size_t ws_size,
                              hipStream_t stream)
{
    const float* hidden  = (const float*)d_in[0];
    const float* W_in    = (const float*)d_in[1];
    const float* W_xproj = (const float*)d_in[2];
    const float* W_dt    = (const float*)d_in[3];
    const float* b_dt    = (const float*)d_in[4];
    const float* A_log_f = (const float*)d_in[5];
    const float* A_log_b = (const float*)d_in[6];
    const float* D_f     = (const float*)d_in[7];
    const float* D_b     = (const float*)d_in[8];
    const float* W_glob  = (const float*)d_in[9];
    const float* b_glob  = (const float*)d_in[10];
    const float* W_gate  = (const float*)d_in[11];
    const float* b_gate  = (const float*)d_in[12];
    const float* W_out   = (const float*)d_in[13];
    float* out = (float*)d_out;

    // workspace layout (~87 MB)
    char* w = (char*)d_ws;
    __bf16* xh    = (__bf16*)w; w += (size_t)BL * DINNER * 2;            // 3.69 MB
    __bf16* xl    = (__bf16*)w; w += (size_t)BL * DINNER * 2;            // 3.69 MB
    float* z_silu = (float*)w;  w += (size_t)BL * DINNER * 4;            // 7.37 MB
    float* dtBC   = (float*)w;  w += (size_t)BL * 48 * 4;                // 0.69 MB
    float* dtb    = (float*)w;  w += (size_t)BL * DINNER * 4;            // 7.37 MB
    float* dub    = (float*)w;  w += (size_t)BL * DINNER * 4;            // 7.37 MB
    __bf16* yh    = (__bf16*)w; w += (size_t)BL * 2 * DINNER * 2;        // 7.37 MB
    __bf16* yl    = (__bf16*)w; w += (size_t)BL * 2 * DINNER * 2;        // 7.37 MB
    float* Pbuf   = (float*)w;  w += (size_t)BB * 2 * NC * DSTATE * DINNER * 4;  // 13.1 MB
    float* Qbuf   = (float*)w;  w += (size_t)BB * 2 * NC * DSTATE * DINNER * 4;  // 13.1 MB
    float* partial= (float*)w;  w += (size_t)BB * NC * 1024 * 4;         // 0.82 MB
    float* ymean  = (float*)w;  w += (size_t)BB * 1024 * 4;
    float* t1     = (float*)w;  w += (size_t)BB * 1024 * 4;
    float* gbuf   = (float*)w;  w += (size_t)BB * 1024 * 4;
    __bf16* hh    = (__bf16*)w; w += (size_t)N_HID * 2;                  // 1.84 MB
    __bf16* hl    = (__bf16*)w; w += (size_t)N_HID * 2;
    __bf16* wih   = (__bf16*)w; w += (size_t)N_WIN * 2;                  // 0.52 MB
    __bf16* wil   = (__bf16*)w; w += (size_t)N_WIN * 2;
    __bf16* wxh   = (__bf16*)w; w += (size_t)N_WXP * 2;
    __bf16* wxl   = (__bf16*)w; w += (size_t)N_WXP * 2;
    __bf16* woh   = (__bf16*)w; w += (size_t)N_WOUT * 2;
    __bf16* wol   = (__bf16*)w; w += (size_t)N_WOUT * 2;
    float* gp2    = (float*)w;  w += (size_t)4 * BL * 48 * 4;            // 2.76 MB (gemm2 K-split)
    float* gpo    = (float*)w;  w += (size_t)2 * BL * DMODEL * 4;        // 7.37 MB (gemm_out K-split)

    // 0) hi/lo split of hidden + weights
    {
        int tot = N_HID + N_WIN + N_WXP + N_WOUT;
        split_inputs<<<dim3((tot + 255) / 256), dim3(256), 0, stream>>>(
            hidden, W_in, W_xproj, W_out, hh, hl, wih, wil, wxh, wxl, woh, wol);
    }
    // 1) xz = hidden @ W_in^T; silu; x -> (xh,xl), z -> z_silu.  2400 waves.
    gemm_tiled<3, 2, 0, 1><<<dim3(600), dim3(256), 0, stream>>>(
        hh, hl, wih, wil, nullptr, z_silu, xh, xl, BL, 2 * DINNER, DMODEL);
    // 2) x_dbl = x @ W_xproj^T, K-split 4 -> partials -> dtBC.  900 waves.
    gemm_tiled<1, 3, 1, 4><<<dim3(225), dim3(256), 0, stream>>>(
        xh, xl, wxh, wxl, gp2, nullptr, nullptr, nullptr, BL, 48, DINNER);
    combineP<4><<<dim3((BL * 48 + 255) / 256), dim3(256), 0, stream>>>(gp2, dtBC, BL * 48);
    // 3) dt precompute (dtv, dtv*u)
    dt_kernel<<<dim3(BL * DINNER / 256), dim3(256), 0, stream>>>(
        dtBC, W_dt, b_dt, xh, xl, dtb, dub);
    // 4) chunked scan
    scan_pass1<<<dim3(NC * 4, 2, BB), dim3(128), 0, stream>>>(
        dtb, dub, dtBC, A_log_f, A_log_b, Pbuf, Qbuf);
    scan_stitch<<<dim3(256), dim3(256), 0, stream>>>(Pbuf, Qbuf);
    scan_pass3<<<dim3(NC * 4, 2, BB), dim3(128), 0, stream>>>(
        dtb, dub, xh, xl, dtBC, A_log_f, A_log_b, D_f, D_b, z_silu, Pbuf, yh, yl, partial);
    // 5) mean
    mean2<<<dim3(16), dim3(256), 0, stream>>>(partial, ymean);
    // 6) gating
    gemv1024<0><<<dim3(1024), dim3(256), 0, stream>>>(ymean, W_glob, b_glob, t1);
    gemv1024<1><<<dim3(1024), dim3(256), 0, stream>>>(t1, W_gate, b_gate, gbuf);
    // 7) y *= g (in place on hi/lo)
    scale_split<<<dim3(BL * 1024 / 4 / 256), dim3(256), 0, stream>>>(yh, yl, gbuf);
    // 8) out = y @ W_out^T, K-split 2 -> partials -> out.  1200 waves.
    gemm_tiled<3, 2, 1, 2><<<dim3(300), dim3(256), 0, stream>>>(
        yh, yl, woh, wol, gpo, nullptr, nullptr, nullptr, BL, DMODEL, 2 * DINNER);
    combineP<2><<<dim3((BL * DMODEL + 255) / 256), dim3(256), 0, stream>>>(gpo, out, BL * DMODEL);
}

// Round 8
// 268.381 us; speedup vs baseline: 6.1235x; 1.0255x over previous
//
#include <hip/hip_runtime.h>
#include <hip/hip_bf16.h>

// Problem constants
#define BB 4
#define LL 900
#define DMODEL 256
#define DSTATE 16
#define DINNER 512
#define DTRANK 16
#define BL (BB*LL)          // 3600
#define NC 75               // scan chunks
#define LC 12               // steps per chunk; NC*LC == LL

typedef __bf16 bf16x8 __attribute__((ext_vector_type(8)));
typedef __bf16 bf16x4 __attribute__((ext_vector_type(4)));
typedef float f32x4 __attribute__((ext_vector_type(4)));

__device__ __forceinline__ float silu_f(float v) { return v / (1.f + __expf(-v)); }

// ---------------------------------------------------------------------------
// One-time hi/lo split of GEMM operands (v ~= hi + lo)
// ---------------------------------------------------------------------------
#define N_HID  (BL*DMODEL)             // 921600
#define N_WIN  (2*DINNER*DMODEL)       // 262144
#define N_WXP  (48*DINNER)             // 24576
#define N_WOUT (DMODEL*2*DINNER)       // 262144
__global__ void split_inputs(const float* __restrict__ hidden, const float* __restrict__ Win,
                             const float* __restrict__ Wxp, const float* __restrict__ Wout,
                             __bf16* __restrict__ hh, __bf16* __restrict__ hl,
                             __bf16* __restrict__ wih, __bf16* __restrict__ wil,
                             __bf16* __restrict__ wxh, __bf16* __restrict__ wxl,
                             __bf16* __restrict__ woh, __bf16* __restrict__ wol)
{
    int idx = blockIdx.x * 256 + threadIdx.x;
    const float* src; __bf16 *oh, *ol; int off;
    if (idx < N_HID)                       { src = hidden; oh = hh;  ol = hl;  off = idx; }
    else if (idx < N_HID+N_WIN)            { src = Win;    oh = wih; ol = wil; off = idx - N_HID; }
    else if (idx < N_HID+N_WIN+N_WXP)      { src = Wxp;    oh = wxh; ol = wxl; off = idx - N_HID - N_WIN; }
    else if (idx < N_HID+N_WIN+N_WXP+N_WOUT){ src = Wout;  oh = woh; ol = wol; off = idx - N_HID - N_WIN - N_WXP; }
    else return;
    float v = src[off];
    __bf16 h = (__bf16)v;
    oh[off] = h;
    ol[off] = (__bf16)(v - (float)h);
}

// ---------------------------------------------------------------------------
// Tiled MFMA GEMM, compile-time K and K-split. Writes fp32 partials only:
// outP[ks][M][N] = A[:, ks-slice] @ B[:, ks-slice]^T   (3 MFMA per 32-chunk)
// Fragment mapping exonerated in rounds 2/3.
// ---------------------------------------------------------------------------
template<int WM, int WN, int K, int KS>
__launch_bounds__(256)
__global__ void gemm_tiled(const __bf16* __restrict__ Ah, const __bf16* __restrict__ Al,
                           const __bf16* __restrict__ Bh, const __bf16* __restrict__ Bl,
                           float* __restrict__ outP, int M, int N)
{
    constexpr int KSL = K / KS;        // K per slice
    constexpr int nk  = KSL >> 5;      // 32-K chunks, compile-time
    int wave = (blockIdx.x * 256 + threadIdx.x) >> 6;
    int ntN = N / (16 * WN);
    int tilesPer = (M / (16 * WM)) * ntN;
    if (wave >= tilesPer * KS) return;
    int ks = wave / tilesPer, t = wave % tilesPer;
    int tm = t / ntN, tn = t % ntN;
    int kOff = ks * KSL;
    int lane = threadIdx.x & 63, q = lane >> 4, r = lane & 15;

    const bf16x8* ArH[WM]; const bf16x8* ArL[WM];
    const bf16x8* BrH[WN]; const bf16x8* BrL[WN];
    #pragma unroll
    for (int mi = 0; mi < WM; ++mi) {
        size_t row = (size_t)(tm * 16 * WM + mi * 16 + r) * K + kOff;
        ArH[mi] = reinterpret_cast<const bf16x8*>(Ah + row);
        ArL[mi] = reinterpret_cast<const bf16x8*>(Al + row);
    }
    #pragma unroll
    for (int ni = 0; ni < WN; ++ni) {
        size_t row = (size_t)(tn * 16 * WN + ni * 16 + r) * K + kOff;
        BrH[ni] = reinterpret_cast<const bf16x8*>(Bh + row);
        BrL[ni] = reinterpret_cast<const bf16x8*>(Bl + row);
    }

    f32x4 acc[WM][WN];
    #pragma unroll
    for (int mi = 0; mi < WM; ++mi)
        #pragma unroll
        for (int ni = 0; ni < WN; ++ni) acc[mi][ni] = (f32x4){0.f,0.f,0.f,0.f};

    #pragma unroll
    for (int kk = 0; kk < nk; ++kk) {
        int idx = kk * 4 + q;
        bf16x8 a_h[WM], a_l[WM], b_h[WN], b_l[WN];
        #pragma unroll
        for (int mi = 0; mi < WM; ++mi) { a_h[mi] = ArH[mi][idx]; a_l[mi] = ArL[mi][idx]; }
        #pragma unroll
        for (int ni = 0; ni < WN; ++ni) { b_h[ni] = BrH[ni][idx]; b_l[ni] = BrL[ni][idx]; }
        #pragma unroll
        for (int mi = 0; mi < WM; ++mi)
            #pragma unroll
            for (int ni = 0; ni < WN; ++ni) {
                acc[mi][ni] = __builtin_amdgcn_mfma_f32_16x16x32_bf16(a_h[mi], b_h[ni], acc[mi][ni], 0, 0, 0);
                acc[mi][ni] = __builtin_amdgcn_mfma_f32_16x16x32_bf16(a_h[mi], b_l[ni], acc[mi][ni], 0, 0, 0);
                acc[mi][ni] = __builtin_amdgcn_mfma_f32_16x16x32_bf16(a_l[mi], b_h[ni], acc[mi][ni], 0, 0, 0);
            }
    }

    float* o0 = outP + (size_t)ks * M * N;
    #pragma unroll
    for (int mi = 0; mi < WM; ++mi)
        #pragma unroll
        for (int ni = 0; ni < WN; ++ni) {
            int col = tn * 16 * WN + ni * 16 + r;
            #pragma unroll
            for (int i = 0; i < 4; ++i) {
                int row = tm * 16 * WM + mi * 16 + q * 4 + i;
                o0[(size_t)row * N + col] = acc[mi][ni][i];
            }
        }
}

// combine gemm1 partials (KS=2) + silu; split cols: <512 -> x hi/lo, >=512 -> z fp32
__global__ void combine_silu(const float* __restrict__ gp, 
                             __bf16* __restrict__ xh, __bf16* __restrict__ xl,
                             float* __restrict__ z_silu)
{
    int i = blockIdx.x * 256 + threadIdx.x;     // BL*1024
    if (i >= BL * 1024) return;
    float s = silu_f(gp[i] + gp[i + (size_t)BL * 1024]);
    int col = i & 1023, row = i >> 10;
    if (col < DINNER) {
        __bf16 h = (__bf16)s;
        xh[(size_t)row * DINNER + col] = h;
        xl[(size_t)row * DINNER + col] = (__bf16)(s - (float)h);
    } else {
        z_silu[(size_t)row * DINNER + (col - DINNER)] = s;
    }
}

// combine K-split partials: out[i] = sum_p in[p*n + i]
template<int P>
__global__ void combineP(const float* __restrict__ in, float* __restrict__ out, int n)
{
    int i = blockIdx.x * 256 + threadIdx.x;
    if (i >= n) return;
    float s = 0.f;
    #pragma unroll
    for (int p = 0; p < P; ++p) s += in[(size_t)p * n + i];
    out[i] = s;
}

// ---------------------------------------------------------------------------
// dt precompute: dtv = softplus(dtBC[:, :16] @ Wdt^T + bdt) -> dtb
// ---------------------------------------------------------------------------
__global__ void dt_kernel(const float* __restrict__ dtBC,
                          const float* __restrict__ Wdt, const float* __restrict__ bdt,
                          float* __restrict__ dtb)
{
    int i = blockIdx.x * 256 + threadIdx.x;       // BL*512
    int d = i & (DINNER - 1);
    size_t row = (size_t)i >> 9;
    const float* xr = dtBC + row * 48;
    const float* wr = Wdt + (size_t)d * DTRANK;
    float s = bdt[d];
    #pragma unroll
    for (int k = 0; k < DTRANK; ++k) s = fmaf(xr[k], wr[k], s);
    dtb[i] = (s > 15.f) ? s : __logf(1.f + __expf(s));
}

// ---------------------------------------------------------------------------
// Scan pass 1: per-chunk zero-init run -> Q (end state), P = exp2(a2*Σdt).
// Layout P/Q: [b][dir][c][n][d] (d fastest).
// ---------------------------------------------------------------------------
__global__ void scan_pass1(const float* __restrict__ dtb,
                           const __bf16* __restrict__ xh, const __bf16* __restrict__ xl,
                           const float* __restrict__ dtBC,
                           const float* __restrict__ AlogF, const float* __restrict__ AlogB,
                           float* __restrict__ Pbuf, float* __restrict__ Qbuf)
{
    int b = blockIdx.z, dir = blockIdx.y;
    int c = blockIdx.x >> 2, dgrp = blockIdx.x & 3;
    int d = dgrp * 128 + threadIdx.x;
    const float* Alog = dir ? AlogB : AlogF;
    float a2[DSTATE];
    #pragma unroll
    for (int n = 0; n < DSTATE; ++n) a2[n] = -__expf(Alog[d * DSTATE + n]) * 1.44269504f;
    float h[DSTATE];
    #pragma unroll
    for (int n = 0; n < DSTATE; ++n) h[n] = 0.f;
    float sdt = 0.f;

    #pragma unroll 4
    for (int il = 0; il < LC; ++il) {
        int i = c * LC + il;
        int l = dir ? (LL - 1 - i) : i;
        size_t base = (size_t)b * LL + l;
        float dtv = dtb[base * DINNER + d];
        float u = (float)xh[base * DINNER + d] + (float)xl[base * DINNER + d];
        float du = dtv * u;
        const f32x4* Bp = reinterpret_cast<const f32x4*>(dtBC + base * 48 + DTRANK);
        f32x4 Bq[4];
        #pragma unroll
        for (int j = 0; j < 4; ++j) Bq[j] = Bp[j];
        sdt += dtv;
        #pragma unroll
        for (int n = 0; n < DSTATE; ++n)
            h[n] = fmaf(exp2f(dtv * a2[n]), h[n], du * Bq[n >> 2][n & 3]);
    }
    size_t o = (((size_t)(b * 2 + dir) * NC + c) * DSTATE) * DINNER + d;
    #pragma unroll
    for (int n = 0; n < DSTATE; ++n) {
        Pbuf[o + (size_t)n * DINNER] = exp2f(sdt * a2[n]);
        Qbuf[o + (size_t)n * DINNER] = h[n];
    }
}

// Pass 2: stitch chunk-initial states IN PLACE (H0 overwrites Pbuf).
__global__ void scan_stitch(float* __restrict__ Pbuf, const float* __restrict__ Qbuf)
{
    int idx = blockIdx.x * 256 + threadIdx.x;   // 65536
    int bd = idx >> 13;           // (b*2+dir)
    int rem = idx & 8191;         // n*512 + d
    float H = 0.f;
    #pragma unroll 5
    for (int c = 0; c < NC; ++c) {
        size_t o = ((size_t)bd * NC + c) * 8192 + rem;
        float Pv = Pbuf[o], Qv = Qbuf[o];
        Pbuf[o] = H;              // store chunk-initial state
        H = fmaf(Pv, H, Qv);
    }
}

// Pass 3: re-run chunk from true initial state (in Pbuf); emit y hi/lo + partials.
// zs (z_silu) is ALREADY silu'd.
__global__ void scan_pass3(const float* __restrict__ dtb,
                           const __bf16* __restrict__ xh, const __bf16* __restrict__ xl,
                           const float* __restrict__ dtBC,
                           const float* __restrict__ AlogF, const float* __restrict__ AlogB,
                           const float* __restrict__ Df, const float* __restrict__ Db,
                           const float* __restrict__ zs,
                           const float* __restrict__ H0buf,
                           __bf16* __restrict__ yh, __bf16* __restrict__ yl,  // [B,L,1024]
                           float* __restrict__ partial)                       // [B,NC,1024]
{
    int b = blockIdx.z, dir = blockIdx.y;
    int c = blockIdx.x >> 2, dgrp = blockIdx.x & 3;
    int d = dgrp * 128 + threadIdx.x;
    const float* Alog = dir ? AlogB : AlogF;
    float a2[DSTATE];
    #pragma unroll
    for (int n = 0; n < DSTATE; ++n) a2[n] = -__expf(Alog[d * DSTATE + n]) * 1.44269504f;
    float Dd = dir ? Db[d] : Df[d];
    size_t o = (((size_t)(b * 2 + dir) * NC + c) * DSTATE) * DINNER + d;
    float h[DSTATE];
    #pragma unroll
    for (int n = 0; n < DSTATE; ++n) h[n] = H0buf[o + (size_t)n * DINNER];
    float ysum = 0.f;

    #pragma unroll 4
    for (int il = 0; il < LC; ++il) {
        int i = c * LC + il;
        int l = dir ? (LL - 1 - i) : i;
        size_t base = (size_t)b * LL + l;
        float dtv = dtb[base * DINNER + d];
        float u = (float)xh[base * DINNER + d] + (float)xl[base * DINNER + d];
        float du = dtv * u;
        const f32x4* Bp = reinterpret_cast<const f32x4*>(dtBC + base * 48 + DTRANK);
        f32x4 Bq[4], Cq[4];
        #pragma unroll
        for (int j = 0; j < 4; ++j) Bq[j] = Bp[j];
        #pragma unroll
        for (int j = 0; j < 4; ++j) Cq[j] = Bp[4 + j];
        float p = 0.f;
        #pragma unroll
        for (int n = 0; n < DSTATE; ++n) {
            h[n] = fmaf(exp2f(dtv * a2[n]), h[n], du * Bq[n >> 2][n & 3]);
            p = fmaf(h[n], Cq[n >> 2][n & 3], p);
        }
        float zg = zs[base * DINNER + d];
        float yv = (p + Dd * u) * zg;
        __bf16 hv = (__bf16)yv;
        size_t yo = base * (2 * DINNER) + dir * DINNER + d;
        yh[yo] = hv;
        yl[yo] = (__bf16)(yv - (float)hv);
        ysum += yv;
    }
    partial[((size_t)b * NC + c) * 1024 + dir * DINNER + d] = ysum;
}

// mean over chunks -> ymean[b,1024]
__global__ void mean2(const float* __restrict__ partial, float* __restrict__ ymean)
{
    int i = blockIdx.x * 256 + threadIdx.x;   // 4096
    int b = i >> 10, ch = i & 1023;
    float s = 0.f;
    for (int c = 0; c < NC; ++c) s += partial[((size_t)b * NC + c) * 1024 + ch];
    ymean[i] = s / (float)LL;
}

// gemv: one wave per (b,j); 4096 waves.
template<int SIG>
__global__ void gemv1024(const float* __restrict__ vin,
                         const float* __restrict__ W,
                         const float* __restrict__ bias,
                         float* __restrict__ vout)
{
    int wv = (blockIdx.x * blockDim.x + threadIdx.x) >> 6;
    int b = wv >> 10, j = wv & 1023;
    int lane = threadIdx.x & 63;
    const float* wr = W + (size_t)j * 1024;
    const float* vr = vin + (size_t)b * 1024;
    float s = 0.f;
    for (int k = lane; k < 1024; k += 64) s = fmaf(vr[k], wr[k], s);
    #pragma unroll
    for (int o = 32; o; o >>= 1) s += __shfl_xor(s, o);
    if (lane == 0) {
        s += bias[j];
        vout[wv] = SIG ? (1.f / (1.f + __expf(-s))) : s;
    }
}

// y(hi/lo) *= g[b,ch], in place, 4 elems/thread
__global__ void scale_split(__bf16* __restrict__ yh, __bf16* __restrict__ yl,
                            const float* __restrict__ g)
{
    int idx = blockIdx.x * 256 + threadIdx.x;   // BL*1024/4
    int e = idx * 4;
    int ch = e & 1023;
    int b = (e >> 10) / LL;
    bf16x4 hv = reinterpret_cast<bf16x4*>(yh)[idx];
    bf16x4 lv = reinterpret_cast<bf16x4*>(yl)[idx];
    f32x4 gv = *reinterpret_cast<const f32x4*>(g + b * 1024 + ch);
    #pragma unroll
    for (int j = 0; j < 4; ++j) {
        float v = ((float)hv[j] + (float)lv[j]) * gv[j];
        __bf16 h = (__bf16)v;
        hv[j] = h;
        lv[j] = (__bf16)(v - (float)h);
    }
    reinterpret_cast<bf16x4*>(yh)[idx] = hv;
    reinterpret_cast<bf16x4*>(yl)[idx] = lv;
}

// ---------------------------------------------------------------------------
extern "C" void kernel_launch(void* const* d_in, const int* in_sizes, int n_in,
                              void* d_out, int out_size, void* d_ws, size_t ws_size,
                              hipStream_t stream)
{
    const float* hidden  = (const float*)d_in[0];
    const float* W_in    = (const float*)d_in[1];
    const float* W_xproj = (const float*)d_in[2];
    const float* W_dt    = (const float*)d_in[3];
    const float* b_dt    = (const float*)d_in[4];
    const float* A_log_f = (const float*)d_in[5];
    const float* A_log_b = (const float*)d_in[6];
    const float* D_f     = (const float*)d_in[7];
    const float* D_b     = (const float*)d_in[8];
    const float* W_glob  = (const float*)d_in[9];
    const float* b_glob  = (const float*)d_in[10];
    const float* W_gate  = (const float*)d_in[11];
    const float* b_gate  = (const float*)d_in[12];
    const float* W_out   = (const float*)d_in[13];
    float* out = (float*)d_out;

    // persistent workspace (~49 MB)
    char* w = (char*)d_ws;
    __bf16* xh    = (__bf16*)w; w += (size_t)BL * DINNER * 2;            // 3.69 MB
    __bf16* xl    = (__bf16*)w; w += (size_t)BL * DINNER * 2;
    float* z_silu = (float*)w;  w += (size_t)BL * DINNER * 4;            // 7.37 MB
    float* dtBC   = (float*)w;  w += (size_t)BL * 48 * 4;
    float* dtb    = (float*)w;  w += (size_t)BL * DINNER * 4;            // 7.37 MB
    __bf16* yh    = (__bf16*)w; w += (size_t)BL * 2 * DINNER * 2;        // 7.37 MB
    __bf16* yl    = (__bf16*)w; w += (size_t)BL * 2 * DINNER * 2;
    float* partial= (float*)w;  w += (size_t)BB * NC * 1024 * 4;         // 1.23 MB
    float* ymean  = (float*)w;  w += (size_t)BB * 1024 * 4;
    float* t1     = (float*)w;  w += (size_t)BB * 1024 * 4;
    float* gbuf   = (float*)w;  w += (size_t)BB * 1024 * 4;
    __bf16* hh    = (__bf16*)w; w += (size_t)N_HID * 2;
    __bf16* hl    = (__bf16*)w; w += (size_t)N_HID * 2;
    __bf16* wih   = (__bf16*)w; w += (size_t)N_WIN * 2;
    __bf16* wil   = (__bf16*)w; w += (size_t)N_WIN * 2;
    __bf16* wxh   = (__bf16*)w; w += (size_t)N_WXP * 2;
    __bf16* wxl   = (__bf16*)w; w += (size_t)N_WXP * 2;
    __bf16* woh   = (__bf16*)w; w += (size_t)N_WOUT * 2;
    __bf16* wol   = (__bf16*)w; w += (size_t)N_WOUT * 2;
    // shared scratch region (~39.3 MB) — uses are strictly sequential:
    //   gp1 (gemm1) -> gp2 (gemm2) -> Pbuf+Qbuf (scan) -> gpo (gemm8)
    float* shared = (float*)w;
    float* gp1  = shared;                                       // 2*BL*1024   = 29.5 MB
    float* gp2  = shared;                                       // 4*BL*48     =  2.8 MB
    float* Pbuf = shared;                                       // 19.66 MB
    float* Qbuf = shared + (size_t)BB * 2 * NC * DSTATE * DINNER;  // +19.66 MB
    float* gpo  = shared;                                       // 4*BL*256    = 14.7 MB

    // 0) hi/lo split of hidden + weights
    {
        int tot = N_HID + N_WIN + N_WXP + N_WOUT;
        split_inputs<<<dim3((tot + 255) / 256), dim3(256), 0, stream>>>(
            hidden, W_in, W_xproj, W_out, hh, hl, wih, wil, wxh, wxl, woh, wol);
    }
    // 1) xz partials = hidden @ W_in^T (KS=2, 4800 waves) -> combine+silu+split
    gemm_tiled<3, 2, 256, 2><<<dim3(1200), dim3(256), 0, stream>>>(
        hh, hl, wih, wil, gp1, BL, 2 * DINNER);
    combine_silu<<<dim3(BL * 1024 / 256), dim3(256), 0, stream>>>(gp1, xh, xl, z_silu);
    // 2) x_dbl = x @ W_xproj^T (KS=4, 900 waves) -> dtBC
    gemm_tiled<1, 3, 512, 4><<<dim3(225), dim3(256), 0, stream>>>(
        xh, xl, wxh, wxl, gp2, BL, 48);
    combineP<4><<<dim3((BL * 48 + 255) / 256), dim3(256), 0, stream>>>(gp2, dtBC, BL * 48);
    // 3) dt precompute
    dt_kernel<<<dim3(BL * DINNER / 256), dim3(256), 0, stream>>>(dtBC, W_dt, b_dt, dtb);
    // 4) chunked scan (4800 waves/pass)
    scan_pass1<<<dim3(NC * 4, 2, BB), dim3(128), 0, stream>>>(
        dtb, xh, xl, dtBC, A_log_f, A_log_b, Pbuf, Qbuf);
    scan_stitch<<<dim3(256), dim3(256), 0, stream>>>(Pbuf, Qbuf);
    scan_pass3<<<dim3(NC * 4, 2, BB), dim3(128), 0, stream>>>(
        dtb, xh, xl, dtBC, A_log_f, A_log_b, D_f, D_b, z_silu, Pbuf, yh, yl, partial);
    // 5) mean
    mean2<<<dim3(16), dim3(256), 0, stream>>>(partial, ymean);
    // 6) gating
    gemv1024<0><<<dim3(1024), dim3(256), 0, stream>>>(ymean, W_glob, b_glob, t1);
    gemv1024<1><<<dim3(1024), dim3(256), 0, stream>>>(t1, W_gate, b_gate, gbuf);
    // 7) y *= g (in place on hi/lo)
    scale_split<<<dim3(BL * 1024 / 4 / 256), dim3(256), 0, stream>>>(yh, yl, gbuf);
    // 8) out = y @ W_out^T (KS=4, 2400 waves) -> combine -> out
    gemm_tiled<3, 2, 1024, 4><<<dim3(600), dim3(256), 0, stream>>>(
        yh, yl, woh, wol, gpo, BL, DMODEL);
    combineP<4><<<dim3((BL * DMODEL + 255) / 256), dim3(256), 0, stream>>>(gpo, out, BL * DMODEL);
}

// Round 10
// 261.379 us; speedup vs baseline: 6.2875x; 1.0268x over previous
//
#include <hip/hip_runtime.h>
#include <hip/hip_bf16.h>

// Problem constants
#define BB 4
#define LL 900
#define DMODEL 256
#define DSTATE 16
#define DINNER 512
#define DTRANK 16
#define BL (BB*LL)          // 3600
#define NC 75               // scan chunks
#define LC 12               // steps per chunk; NC*LC == LL

typedef __bf16 bf16x8 __attribute__((ext_vector_type(8)));
typedef __bf16 bf16x4 __attribute__((ext_vector_type(4)));
typedef float f32x4 __attribute__((ext_vector_type(4)));

__device__ __forceinline__ float silu_f(float v) { return v / (1.f + __expf(-v)); }

// ---------------------------------------------------------------------------
// One-time hi/lo split of GEMM operands (v ~= hi + lo)
// ---------------------------------------------------------------------------
#define N_HID  (BL*DMODEL)             // 921600
#define N_WIN  (2*DINNER*DMODEL)       // 262144
#define N_WXP  (48*DINNER)             // 24576
#define N_WOUT (DMODEL*2*DINNER)       // 262144
__global__ void split_inputs(const float* __restrict__ hidden, const float* __restrict__ Win,
                             const float* __restrict__ Wxp, const float* __restrict__ Wout,
                             __bf16* __restrict__ hh, __bf16* __restrict__ hl,
                             __bf16* __restrict__ wih, __bf16* __restrict__ wil,
                             __bf16* __restrict__ wxh, __bf16* __restrict__ wxl,
                             __bf16* __restrict__ woh, __bf16* __restrict__ wol)
{
    int idx = blockIdx.x * 256 + threadIdx.x;
    const float* src; __bf16 *oh, *ol; int off;
    if (idx < N_HID)                       { src = hidden; oh = hh;  ol = hl;  off = idx; }
    else if (idx < N_HID+N_WIN)            { src = Win;    oh = wih; ol = wil; off = idx - N_HID; }
    else if (idx < N_HID+N_WIN+N_WXP)      { src = Wxp;    oh = wxh; ol = wxl; off = idx - N_HID - N_WIN; }
    else if (idx < N_HID+N_WIN+N_WXP+N_WOUT){ src = Wout;  oh = woh; ol = wol; off = idx - N_HID - N_WIN - N_WXP; }
    else return;
    float v = src[off];
    __bf16 h = (__bf16)v;
    oh[off] = h;
    ol[off] = (__bf16)(v - (float)h);
}

// ---------------------------------------------------------------------------
// gemm1: xz = hidden @ W_in^T (M=3600,N=1024,K=256), fused silu epilogue.
// Wave tile 48x32 (WM=3,WN=2); 2400 waves; compile-time K, full unroll.
// cols <512 -> x hi/lo bf16; cols >=512 -> z fp32 (already silu'd).
// ---------------------------------------------------------------------------
__launch_bounds__(256)
__global__ void gemm_silu(const __bf16* __restrict__ Ah, const __bf16* __restrict__ Al,
                          const __bf16* __restrict__ Bh, const __bf16* __restrict__ Bl,
                          __bf16* __restrict__ xh, __bf16* __restrict__ xl,
                          float* __restrict__ z_silu)
{
    constexpr int WM = 3, WN = 2, K = 256, nk = K >> 5;
    constexpr int M = BL, N = 2 * DINNER;
    int wave = (blockIdx.x * 256 + threadIdx.x) >> 6;
    int ntN = N / (16 * WN);
    if (wave >= (M / (16 * WM)) * ntN) return;
    int tm = wave / ntN, tn = wave % ntN;
    int lane = threadIdx.x & 63, q = lane >> 4, r = lane & 15;

    const bf16x8* ArH[WM]; const bf16x8* ArL[WM];
    const bf16x8* BrH[WN]; const bf16x8* BrL[WN];
    #pragma unroll
    for (int mi = 0; mi < WM; ++mi) {
        size_t row = (size_t)(tm * 16 * WM + mi * 16 + r) * K;
        ArH[mi] = reinterpret_cast<const bf16x8*>(Ah + row);
        ArL[mi] = reinterpret_cast<const bf16x8*>(Al + row);
    }
    #pragma unroll
    for (int ni = 0; ni < WN; ++ni) {
        size_t row = (size_t)(tn * 16 * WN + ni * 16 + r) * K;
        BrH[ni] = reinterpret_cast<const bf16x8*>(Bh + row);
        BrL[ni] = reinterpret_cast<const bf16x8*>(Bl + row);
    }
    f32x4 acc[WM][WN];
    #pragma unroll
    for (int mi = 0; mi < WM; ++mi)
        #pragma unroll
        for (int ni = 0; ni < WN; ++ni) acc[mi][ni] = (f32x4){0.f,0.f,0.f,0.f};

    #pragma unroll
    for (int kk = 0; kk < nk; ++kk) {
        int idx = kk * 4 + q;
        bf16x8 a_h[WM], a_l[WM], b_h[WN], b_l[WN];
        #pragma unroll
        for (int mi = 0; mi < WM; ++mi) { a_h[mi] = ArH[mi][idx]; a_l[mi] = ArL[mi][idx]; }
        #pragma unroll
        for (int ni = 0; ni < WN; ++ni) { b_h[ni] = BrH[ni][idx]; b_l[ni] = BrL[ni][idx]; }
        #pragma unroll
        for (int mi = 0; mi < WM; ++mi)
            #pragma unroll
            for (int ni = 0; ni < WN; ++ni) {
                acc[mi][ni] = __builtin_amdgcn_mfma_f32_16x16x32_bf16(a_h[mi], b_h[ni], acc[mi][ni], 0, 0, 0);
                acc[mi][ni] = __builtin_amdgcn_mfma_f32_16x16x32_bf16(a_h[mi], b_l[ni], acc[mi][ni], 0, 0, 0);
                acc[mi][ni] = __builtin_amdgcn_mfma_f32_16x16x32_bf16(a_l[mi], b_h[ni], acc[mi][ni], 0, 0, 0);
            }
    }
    #pragma unroll
    for (int mi = 0; mi < WM; ++mi)
        #pragma unroll
        for (int ni = 0; ni < WN; ++ni) {
            int col = tn * 16 * WN + ni * 16 + r;
            #pragma unroll
            for (int i = 0; i < 4; ++i) {
                int row = tm * 16 * WM + mi * 16 + q * 4 + i;
                float s = silu_f(acc[mi][ni][i]);
                if (col < DINNER) {
                    __bf16 h = (__bf16)s;
                    xh[(size_t)row * DINNER + col] = h;
                    xl[(size_t)row * DINNER + col] = (__bf16)(s - (float)h);
                } else {
                    z_silu[(size_t)row * DINNER + (col - DINNER)] = s;
                }
            }
        }
}

// ---------------------------------------------------------------------------
// gemm2 + dt fused: x_dbl = x @ W_xproj^T (M=3600,N=48,K=512), KS=4 K-split
// combined in LDS, then dt = softplus(dt_r @ Wdt^T + bdt) for the 16 rows.
// Block = 4 waves = one 16x48 tile, one K-slice each. Grid 225 blocks.
// ---------------------------------------------------------------------------
__launch_bounds__(256)
__global__ void gemm2_dt(const __bf16* __restrict__ Ah, const __bf16* __restrict__ Al,
                         const __bf16* __restrict__ Bh, const __bf16* __restrict__ Bl,
                         const float* __restrict__ Wdt, const float* __restrict__ bdt,
                         float* __restrict__ dtBC, float* __restrict__ dtb)
{
    constexpr int WN = 3, K = 512, KSL = 128, nk = KSL >> 5;   // 4 chunks
    __shared__ float lds[4][16 * 48];
    int tm = blockIdx.x;                       // 225 tiles (16 rows each)
    int wv = threadIdx.x >> 6;                 // ks = wave id
    int kOff = wv * KSL;
    int lane = threadIdx.x & 63, q = lane >> 4, r = lane & 15;

    const bf16x8* ArH = reinterpret_cast<const bf16x8*>(Ah + (size_t)(tm * 16 + r) * K + kOff);
    const bf16x8* ArL = reinterpret_cast<const bf16x8*>(Al + (size_t)(tm * 16 + r) * K + kOff);
    const bf16x8* BrH[WN]; const bf16x8* BrL[WN];
    #pragma unroll
    for (int ni = 0; ni < WN; ++ni) {
        size_t row = (size_t)(ni * 16 + r) * K + kOff;
        BrH[ni] = reinterpret_cast<const bf16x8*>(Bh + row);
        BrL[ni] = reinterpret_cast<const bf16x8*>(Bl + row);
    }
    f32x4 acc[WN];
    #pragma unroll
    for (int ni = 0; ni < WN; ++ni) acc[ni] = (f32x4){0.f,0.f,0.f,0.f};

    #pragma unroll
    for (int kk = 0; kk < nk; ++kk) {
        int idx = kk * 4 + q;
        bf16x8 a_h = ArH[idx], a_l = ArL[idx];
        bf16x8 b_h[WN], b_l[WN];
        #pragma unroll
        for (int ni = 0; ni < WN; ++ni) { b_h[ni] = BrH[ni][idx]; b_l[ni] = BrL[ni][idx]; }
        #pragma unroll
        for (int ni = 0; ni < WN; ++ni) {
            acc[ni] = __builtin_amdgcn_mfma_f32_16x16x32_bf16(a_h, b_h[ni], acc[ni], 0, 0, 0);
            acc[ni] = __builtin_amdgcn_mfma_f32_16x16x32_bf16(a_h, b_l[ni], acc[ni], 0, 0, 0);
            acc[ni] = __builtin_amdgcn_mfma_f32_16x16x32_bf16(a_l, b_h[ni], acc[ni], 0, 0, 0);
        }
    }
    // stash per-slice fragments
    #pragma unroll
    for (int ni = 0; ni < WN; ++ni) {
        int col = ni * 16 + r;
        #pragma unroll
        for (int i = 0; i < 4; ++i)
            lds[wv][(q * 4 + i) * 48 + col] = acc[ni][i];
    }
    __syncthreads();
    // combine 4 slices; write dtBC; keep combined tile in lds[0]
    for (int e = threadIdx.x; e < 16 * 48; e += 256) {
        float s = lds[0][e] + lds[1][e] + lds[2][e] + lds[3][e];
        lds[0][e] = s;
        int row = e / 48, col = e % 48;
        dtBC[(size_t)(tm * 16 + row) * 48 + col] = s;
    }
    __syncthreads();
    // dt for 16 rows x 512 d
    for (int it = 0; it < 32; ++it) {
        int e = threadIdx.x + it * 256;        // 8192
        int row = e >> 9, d = e & 511;
        const float* wr = Wdt + (size_t)d * DTRANK;
        float s = bdt[d];
        #pragma unroll
        for (int k = 0; k < DTRANK; ++k) s = fmaf(lds[0][row * 48 + k], wr[k], s);
        dtb[(size_t)(tm * 16 + row) * DINNER + d] = (s > 15.f) ? s : __logf(1.f + __expf(s));
    }
}

// ---------------------------------------------------------------------------
// Scan pass 1: per-chunk zero-init run -> Q (end state), P = exp2(a2*Σdt).
// Layout P/Q: [b][dir][c][n][d] (d fastest).
// ---------------------------------------------------------------------------
__global__ void scan_pass1(const float* __restrict__ dtb,
                           const __bf16* __restrict__ xh, const __bf16* __restrict__ xl,
                           const float* __restrict__ dtBC,
                           const float* __restrict__ AlogF, const float* __restrict__ AlogB,
                           float* __restrict__ Pbuf, float* __restrict__ Qbuf)
{
    int b = blockIdx.z, dir = blockIdx.y;
    int c = blockIdx.x >> 2, dgrp = blockIdx.x & 3;
    int d = dgrp * 128 + threadIdx.x;
    const float* Alog = dir ? AlogB : AlogF;
    float a2[DSTATE];
    #pragma unroll
    for (int n = 0; n < DSTATE; ++n) a2[n] = -__expf(Alog[d * DSTATE + n]) * 1.44269504f;
    float h[DSTATE];
    #pragma unroll
    for (int n = 0; n < DSTATE; ++n) h[n] = 0.f;
    float sdt = 0.f;

    #pragma unroll 4
    for (int il = 0; il < LC; ++il) {
        int i = c * LC + il;
        int l = dir ? (LL - 1 - i) : i;
        size_t base = (size_t)b * LL + l;
        float dtv = dtb[base * DINNER + d];
        float u = (float)xh[base * DINNER + d] + (float)xl[base * DINNER + d];
        float du = dtv * u;
        const f32x4* Bp = reinterpret_cast<const f32x4*>(dtBC + base * 48 + DTRANK);
        f32x4 Bq[4];
        #pragma unroll
        for (int j = 0; j < 4; ++j) Bq[j] = Bp[j];
        sdt += dtv;
        #pragma unroll
        for (int n = 0; n < DSTATE; ++n)
            h[n] = fmaf(exp2f(dtv * a2[n]), h[n], du * Bq[n >> 2][n & 3]);
    }
    size_t o = (((size_t)(b * 2 + dir) * NC + c) * DSTATE) * DINNER + d;
    #pragma unroll
    for (int n = 0; n < DSTATE; ++n) {
        Pbuf[o + (size_t)n * DINNER] = exp2f(sdt * a2[n]);
        Qbuf[o + (size_t)n * DINNER] = h[n];
    }
}

// Pass 2: stitch in place (H0 overwrites Pbuf), batched 15-wide prefetch.
__global__ void scan_stitch(float* __restrict__ Pbuf, const float* __restrict__ Qbuf)
{
    int idx = blockIdx.x * 256 + threadIdx.x;   // 65536
    int bd = idx >> 13;
    int rem = idx & 8191;
    size_t base = (size_t)bd * NC * 8192 + rem;
    float H = 0.f;
    for (int cb = 0; cb < NC; cb += 15) {
        float Pv[15], Qv[15];
        #pragma unroll
        for (int j = 0; j < 15; ++j) {
            size_t o = base + (size_t)(cb + j) * 8192;
            Pv[j] = Pbuf[o];
            Qv[j] = Qbuf[o];
        }
        #pragma unroll
        for (int j = 0; j < 15; ++j) {
            Pbuf[base + (size_t)(cb + j) * 8192] = H;
            H = fmaf(Pv[j], H, Qv[j]);
        }
    }
}

// Pass 3: re-run chunk from true initial state (in Pbuf); emit y hi/lo + partials.
// zs (z_silu) is ALREADY silu'd.
__global__ void scan_pass3(const float* __restrict__ dtb,
                           const __bf16* __restrict__ xh, const __bf16* __restrict__ xl,
                           const float* __restrict__ dtBC,
                           const float* __restrict__ AlogF, const float* __restrict__ AlogB,
                           const float* __restrict__ Df, const float* __restrict__ Db,
                           const float* __restrict__ zs,
                           const float* __restrict__ H0buf,
                           __bf16* __restrict__ yh, __bf16* __restrict__ yl,  // [B,L,1024]
                           float* __restrict__ partial)                       // [B,NC,1024]
{
    int b = blockIdx.z, dir = blockIdx.y;
    int c = blockIdx.x >> 2, dgrp = blockIdx.x & 3;
    int d = dgrp * 128 + threadIdx.x;
    const float* Alog = dir ? AlogB : AlogF;
    float a2[DSTATE];
    #pragma unroll
    for (int n = 0; n < DSTATE; ++n) a2[n] = -__expf(Alog[d * DSTATE + n]) * 1.44269504f;
    float Dd = dir ? Db[d] : Df[d];
    size_t o = (((size_t)(b * 2 + dir) * NC + c) * DSTATE) * DINNER + d;
    float h[DSTATE];
    #pragma unroll
    for (int n = 0; n < DSTATE; ++n) h[n] = H0buf[o + (size_t)n * DINNER];
    float ysum = 0.f;

    #pragma unroll 4
    for (int il = 0; il < LC; ++il) {
        int i = c * LC + il;
        int l = dir ? (LL - 1 - i) : i;
        size_t base = (size_t)b * LL + l;
        float dtv = dtb[base * DINNER + d];
        float u = (float)xh[base * DINNER + d] + (float)xl[base * DINNER + d];
        float du = dtv * u;
        const f32x4* Bp = reinterpret_cast<const f32x4*>(dtBC + base * 48 + DTRANK);
        f32x4 Bq[4], Cq[4];
        #pragma unroll
        for (int j = 0; j < 4; ++j) Bq[j] = Bp[j];
        #pragma unroll
        for (int j = 0; j < 4; ++j) Cq[j] = Bp[4 + j];
        float p = 0.f;
        #pragma unroll
        for (int n = 0; n < DSTATE; ++n) {
            h[n] = fmaf(exp2f(dtv * a2[n]), h[n], du * Bq[n >> 2][n & 3]);
            p = fmaf(h[n], Cq[n >> 2][n & 3], p);
        }
        float zg = zs[base * DINNER + d];
        float yv = (p + Dd * u) * zg;
        __bf16 hv = (__bf16)yv;
        size_t yo = base * (2 * DINNER) + dir * DINNER + d;
        yh[yo] = hv;
        yl[yo] = (__bf16)(yv - (float)hv);
        ysum += yv;
    }
    partial[((size_t)b * NC + c) * 1024 + dir * DINNER + d] = ysum;
}

// mean over chunks -> ymean[b,1024]
__global__ void mean2(const float* __restrict__ partial, float* __restrict__ ymean)
{
    int i = blockIdx.x * 256 + threadIdx.x;   // 4096
    int b = i >> 10, ch = i & 1023;
    float s = 0.f;
    #pragma unroll 5
    for (int c = 0; c < NC; ++c) s += partial[((size_t)b * NC + c) * 1024 + ch];
    ymean[i] = s / (float)LL;
}

// gemv: one wave per (b,j); 4096 waves.
template<int SIG>
__global__ void gemv1024(const float* __restrict__ vin,
                         const float* __restrict__ W,
                         const float* __restrict__ bias,
                         float* __restrict__ vout)
{
    int wv = (blockIdx.x * blockDim.x + threadIdx.x) >> 6;
    int b = wv >> 10, j = wv & 1023;
    int lane = threadIdx.x & 63;
    const float* wr = W + (size_t)j * 1024;
    const float* vr = vin + (size_t)b * 1024;
    float s = 0.f;
    for (int k = lane; k < 1024; k += 64) s = fmaf(vr[k], wr[k], s);
    #pragma unroll
    for (int o = 32; o; o >>= 1) s += __shfl_xor(s, o);
    if (lane == 0) {
        s += bias[j];
        vout[wv] = SIG ? (1.f / (1.f + __expf(-s))) : s;
    }
}

// y(hi/lo) *= g[b,ch], in place, 4 elems/thread
__global__ void scale_split(__bf16* __restrict__ yh, __bf16* __restrict__ yl,
                            const float* __restrict__ g)
{
    int idx = blockIdx.x * 256 + threadIdx.x;   // BL*1024/4
    int e = idx * 4;
    int ch = e & 1023;
    int b = (e >> 10) / LL;
    bf16x4 hv = reinterpret_cast<bf16x4*>(yh)[idx];
    bf16x4 lv = reinterpret_cast<bf16x4*>(yl)[idx];
    f32x4 gv = *reinterpret_cast<const f32x4*>(g + b * 1024 + ch);
    #pragma unroll
    for (int j = 0; j < 4; ++j) {
        float v = ((float)hv[j] + (float)lv[j]) * gv[j];
        __bf16 h = (__bf16)v;
        hv[j] = h;
        lv[j] = (__bf16)(v - (float)h);
    }
    reinterpret_cast<bf16x4*>(yh)[idx] = hv;
    reinterpret_cast<bf16x4*>(yl)[idx] = lv;
}

// ---------------------------------------------------------------------------
// gemm8: out = y @ W_out^T (M=3600,N=256,K=1024), KS=2 combined in LDS.
// Block = 4 waves = 2 tiles x 2 K-halves. Wave tile 48x32. Grid 300 blocks.
// ---------------------------------------------------------------------------
__launch_bounds__(256)
__global__ void gemm8_comb(const __bf16* __restrict__ Ah, const __bf16* __restrict__ Al,
                           const __bf16* __restrict__ Bh, const __bf16* __restrict__ Bl,
                           float* __restrict__ out)
{
    constexpr int WM = 3, WN = 2, K = 1024, KSL = 512, nk = KSL >> 5;  // 16 chunks
    constexpr int N = DMODEL, ntN = N / (16 * WN);                      // 8
    __shared__ float lds[2][2][48 * 32];
    int wv = threadIdx.x >> 6;
    int tLoc = wv >> 1, ks = wv & 1;
    int tIdx = blockIdx.x * 2 + tLoc;          // 600 tiles
    int tm = tIdx / ntN, tn = tIdx % ntN;
    int kOff = ks * KSL;
    int lane = threadIdx.x & 63, q = lane >> 4, r = lane & 15;

    const bf16x8* ArH[WM]; const bf16x8* ArL[WM];
    const bf16x8* BrH[WN]; const bf16x8* BrL[WN];
    #pragma unroll
    for (int mi = 0; mi < WM; ++mi) {
        size_t row = (size_t)(tm * 48 + mi * 16 + r) * K + kOff;
        ArH[mi] = reinterpret_cast<const bf16x8*>(Ah + row);
        ArL[mi] = reinterpret_cast<const bf16x8*>(Al + row);
    }
    #pragma unroll
    for (int ni = 0; ni < WN; ++ni) {
        size_t row = (size_t)(tn * 32 + ni * 16 + r) * K + kOff;
        BrH[ni] = reinterpret_cast<const bf16x8*>(Bh + row);
        BrL[ni] = reinterpret_cast<const bf16x8*>(Bl + row);
    }
    f32x4 acc[WM][WN];
    #pragma unroll
    for (int mi = 0; mi < WM; ++mi)
        #pragma unroll
        for (int ni = 0; ni < WN; ++ni) acc[mi][ni] = (f32x4){0.f,0.f,0.f,0.f};

    #pragma unroll
    for (int kk = 0; kk < nk; ++kk) {
        int idx = kk * 4 + q;
        bf16x8 a_h[WM], a_l[WM], b_h[WN], b_l[WN];
        #pragma unroll
        for (int mi = 0; mi < WM; ++mi) { a_h[mi] = ArH[mi][idx]; a_l[mi] = ArL[mi][idx]; }
        #pragma unroll
        for (int ni = 0; ni < WN; ++ni) { b_h[ni] = BrH[ni][idx]; b_l[ni] = BrL[ni][idx]; }
        #pragma unroll
        for (int mi = 0; mi < WM; ++mi)
            #pragma unroll
            for (int ni = 0; ni < WN; ++ni) {
                acc[mi][ni] = __builtin_amdgcn_mfma_f32_16x16x32_bf16(a_h[mi], b_h[ni], acc[mi][ni], 0, 0, 0);
                acc[mi][ni] = __builtin_amdgcn_mfma_f32_16x16x32_bf16(a_h[mi], b_l[ni], acc[mi][ni], 0, 0, 0);
                acc[mi][ni] = __builtin_amdgcn_mfma_f32_16x16x32_bf16(a_l[mi], b_h[ni], acc[mi][ni], 0, 0, 0);
            }
    }
    #pragma unroll
    for (int mi = 0; mi < WM; ++mi)
        #pragma unroll
        for (int ni = 0; ni < WN; ++ni) {
            int col = ni * 16 + r;
            #pragma unroll
            for (int i = 0; i < 4; ++i)
                lds[tLoc][ks][(mi * 16 + q * 4 + i) * 32 + col] = acc[mi][ni][i];
        }
    __syncthreads();
    // FIXED (round-9 bug): packed 3072-elem range, tl = e/1536, idx = e%1536.
    // Round 9 decoded as e>>11 / e&2047, leaving idx 1024..1535 of odd tiles unwritten.
    for (int e = threadIdx.x; e < 2 * 1536; e += 256) {
        int tl = (e >= 1536) ? 1 : 0;
        int idx = e - tl * 1536;
        int row = idx >> 5, col = idx & 31;
        int tg = blockIdx.x * 2 + tl;
        int gm = (tg / ntN) * 48 + row, gn = (tg % ntN) * 32 + col;
        out[(size_t)gm * N + gn] = lds[tl][0][idx] + lds[tl][1][idx];
    }
}

// ---------------------------------------------------------------------------
extern "C" void kernel_launch(void* const* d_in, const int* in_sizes, int n_in,
                              void* d_out, int out_size, void* d_ws, size_t ws_size,
                              hipStream_t stream)
{
    const float* hidden  = (const float*)d_in[0];
    const float* W_in    = (const float*)d_in[1];
    const float* W_xproj = (const float*)d_in[2];
    const float* W_dt    = (const float*)d_in[3];
    const float* b_dt    = (const float*)d_in[4];
    const float* A_log_f = (const float*)d_in[5];
    const float* A_log_b = (const float*)d_in[6];
    const float* D_f     = (const float*)d_in[7];
    const float* D_b     = (const float*)d_in[8];
    const float* W_glob  = (const float*)d_in[9];
    const float* b_glob  = (const float*)d_in[10];
    const float* W_gate  = (const float*)d_in[11];
    const float* b_gate  = (const float*)d_in[12];
    const float* W_out   = (const float*)d_in[13];
    float* out = (float*)d_out;

    // workspace (~75 MB)
    char* w = (char*)d_ws;
    __bf16* xh    = (__bf16*)w; w += (size_t)BL * DINNER * 2;
    __bf16* xl    = (__bf16*)w; w += (size_t)BL * DINNER * 2;
    float* z_silu = (float*)w;  w += (size_t)BL * DINNER * 4;
    float* dtBC   = (float*)w;  w += (size_t)BL * 48 * 4;
    float* dtb    = (float*)w;  w += (size_t)BL * DINNER * 4;
    __bf16* yh    = (__bf16*)w; w += (size_t)BL * 2 * DINNER * 2;
    __bf16* yl    = (__bf16*)w; w += (size_t)BL * 2 * DINNER * 2;
    float* partial= (float*)w;  w += (size_t)BB * NC * 1024 * 4;
    float* ymean  = (float*)w;  w += (size_t)BB * 1024 * 4;
    float* t1     = (float*)w;  w += (size_t)BB * 1024 * 4;
    float* gbuf   = (float*)w;  w += (size_t)BB * 1024 * 4;
    __bf16* hh    = (__bf16*)w; w += (size_t)N_HID * 2;
    __bf16* hl    = (__bf16*)w; w += (size_t)N_HID * 2;
    __bf16* wih   = (__bf16*)w; w += (size_t)N_WIN * 2;
    __bf16* wil   = (__bf16*)w; w += (size_t)N_WIN * 2;
    __bf16* wxh   = (__bf16*)w; w += (size_t)N_WXP * 2;
    __bf16* wxl   = (__bf16*)w; w += (size_t)N_WXP * 2;
    __bf16* woh   = (__bf16*)w; w += (size_t)N_WOUT * 2;
    __bf16* wol   = (__bf16*)w; w += (size_t)N_WOUT * 2;
    float* Pbuf   = (float*)w;  w += (size_t)BB * 2 * NC * DSTATE * DINNER * 4;  // 19.7 MB
    float* Qbuf   = (float*)w;  w += (size_t)BB * 2 * NC * DSTATE * DINNER * 4;  // 19.7 MB

    // 0) hi/lo split of hidden + weights
    {
        int tot = N_HID + N_WIN + N_WXP + N_WOUT;
        split_inputs<<<dim3((tot + 255) / 256), dim3(256), 0, stream>>>(
            hidden, W_in, W_xproj, W_out, hh, hl, wih, wil, wxh, wxl, woh, wol);
    }
    // 1) xz = hidden @ W_in^T, fused silu+split (2400 waves)
    gemm_silu<<<dim3(600), dim3(256), 0, stream>>>(hh, hl, wih, wil, xh, xl, z_silu);
    // 2) x_dbl + dt, fused (225 blocks)
    gemm2_dt<<<dim3(225), dim3(256), 0, stream>>>(xh, xl, wxh, wxl, W_dt, b_dt, dtBC, dtb);
    // 3) chunked scan (4800 waves/pass)
    scan_pass1<<<dim3(NC * 4, 2, BB), dim3(128), 0, stream>>>(
        dtb, xh, xl, dtBC, A_log_f, A_log_b, Pbuf, Qbuf);
    scan_stitch<<<dim3(256), dim3(256), 0, stream>>>(Pbuf, Qbuf);
    scan_pass3<<<dim3(NC * 4, 2, BB), dim3(128), 0, stream>>>(
        dtb, xh, xl, dtBC, A_log_f, A_log_b, D_f, D_b, z_silu, Pbuf, yh, yl, partial);
    // 4) mean
    mean2<<<dim3(16), dim3(256), 0, stream>>>(partial, ymean);
    // 5) gating
    gemv1024<0><<<dim3(1024), dim3(256), 0, stream>>>(ymean, W_glob, b_glob, t1);
    gemv1024<1><<<dim3(1024), dim3(256), 0, stream>>>(t1, W_gate, b_gate, gbuf);
    // 6) y *= g
    scale_split<<<dim3(BL * 1024 / 4 / 256), dim3(256), 0, stream>>>(yh, yl, gbuf);
    // 7) out = y @ W_out^T, KS=2 LDS-combined (300 blocks)
    gemm8_comb<<<dim3(300), dim3(256), 0, stream>>>(yh, yl, woh, wol, out);
}